// Round 1
// baseline (2247.746 us; speedup 1.0000x reference)
//
#include <hip/hip_runtime.h>
#include <cstddef>

#define NN 100000
#define NE 3200000
#define FIN 128
#define HID 16
#define NC 40

// K1: X0 = x@W1[0]; D = x@W1[1] - X0; XR = x@root1 + bias1   (per node, 48 outputs)
__global__ __launch_bounds__(256) void k_gemm1(const float* __restrict__ x,
    const float* __restrict__ W1, const float* __restrict__ root1,
    const float* __restrict__ bias1,
    float* __restrict__ X0, float* __restrict__ D, float* __restrict__ XR) {
  __shared__ float wT[48][132];   // transposed weights: wT[j][k]
  __shared__ float xs[16][132];   // 16 node rows, padded stride
  int t = threadIdx.x;
  for (int i = t; i < 48 * FIN; i += 256) {
    int j = i >> 7, k = i & 127;
    float v;
    if (j < 16)      v = W1[k * 16 + j];
    else if (j < 32) v = W1[2048 + k * 16 + (j - 16)];
    else             v = root1[k * 16 + (j - 32)];
    wT[j][k] = v;
  }
  const float4* x4 = (const float4*)(x + (size_t)blockIdx.x * 16 * FIN);
  for (int i = t; i < 16 * FIN / 4; i += 256) {
    float4 v = x4[i];
    int r = i >> 5, c = (i & 31) << 2;
    *(float4*)&xs[r][c] = v;
  }
  __syncthreads();
  int nl = t >> 4, j = t & 15;
  float a0 = 0.f, a1 = 0.f, ar = 0.f;
#pragma unroll
  for (int k = 0; k < FIN; k += 4) {
    float4 xv = *(const float4*)&xs[nl][k];
    float4 w0 = *(const float4*)&wT[j][k];
    float4 w1 = *(const float4*)&wT[j + 16][k];
    float4 wr = *(const float4*)&wT[j + 32][k];
    a0 += xv.x * w0.x + xv.y * w0.y + xv.z * w0.z + xv.w * w0.w;
    a1 += xv.x * w1.x + xv.y * w1.y + xv.z * w1.z + xv.w * w1.w;
    ar += xv.x * wr.x + xv.y * wr.y + xv.z * wr.z + xv.w * wr.w;
  }
  size_t idx = (size_t)(blockIdx.x * 16 + nl) * HID + j;
  X0[idx] = a0;
  D[idx]  = a1 - a0;
  XR[idx] = ar + bias1[j];
}

// K2: edge pass 1 — agg[dst] += X0[src] + u*D[src];  cnt[dst] += 1
__global__ __launch_bounds__(256) void k_edge1(const int* __restrict__ ei,
    const float* __restrict__ ea, const float* __restrict__ X0,
    const float* __restrict__ D, float* __restrict__ agg, float* __restrict__ cnt) {
  int tid = blockIdx.x * 256 + threadIdx.x;
  int e = tid >> 2, c = tid & 3;
  if (e >= NE) return;
  int s = ei[e], d = ei[NE + e];
  float uu = ea[e];
  float4 x0 = *(const float4*)(X0 + (size_t)s * HID + c * 4);
  float4 dd = *(const float4*)(D  + (size_t)s * HID + c * 4);
  float* ap = agg + (size_t)d * HID + c * 4;
  atomicAdd(ap + 0, x0.x + uu * dd.x);
  atomicAdd(ap + 1, x0.y + uu * dd.y);
  atomicAdd(ap + 2, x0.z + uu * dd.z);
  atomicAdd(ap + 3, x0.w + uu * dd.w);
  if (c == 0) atomicAdd(cnt + d, 1.0f);
}

// K3: h = elu(agg/max(cnt,1) + XR)   (in place over agg)
__global__ __launch_bounds__(256) void k_node1(float* __restrict__ aggh,
    const float* __restrict__ xr, const float* __restrict__ cnt) {
  int i = blockIdx.x * 256 + threadIdx.x;       // float4 index
  if (i >= NN * HID / 4) return;
  int n = i >> 2;
  float ic = 1.0f / fmaxf(cnt[n], 1.0f);
  float4 a = ((const float4*)aggh)[i];
  float4 r = ((const float4*)xr)[i];
  float4 h;
  h.x = a.x * ic + r.x;
  h.y = a.y * ic + r.y;
  h.z = a.z * ic + r.z;
  h.w = a.w * ic + r.w;
  h.x = h.x > 0.f ? h.x : expm1f(h.x);
  h.y = h.y > 0.f ? h.y : expm1f(h.y);
  h.z = h.z > 0.f ? h.z : expm1f(h.z);
  h.w = h.w > 0.f ? h.w : expm1f(h.w);
  ((float4*)aggh)[i] = h;
}

// K4: edge pass 2 — A0[dst] += (1-u)*h[src];  A1[dst] += u*h[src]
__global__ __launch_bounds__(256) void k_edge2(const int* __restrict__ ei,
    const float* __restrict__ ea, const float* __restrict__ h,
    float* __restrict__ A0, float* __restrict__ A1) {
  int tid = blockIdx.x * 256 + threadIdx.x;
  int e = tid >> 2, c = tid & 3;
  if (e >= NE) return;
  int s = ei[e], d = ei[NE + e];
  float uu = ea[e];
  float b0 = 1.0f - uu;
  float4 hv = *(const float4*)(h + (size_t)s * HID + c * 4);
  float* p0 = A0 + (size_t)d * HID + c * 4;
  float* p1 = A1 + (size_t)d * HID + c * 4;
  atomicAdd(p0 + 0, b0 * hv.x);
  atomicAdd(p0 + 1, b0 * hv.y);
  atomicAdd(p0 + 2, b0 * hv.z);
  atomicAdd(p0 + 3, b0 * hv.w);
  atomicAdd(p1 + 0, uu * hv.x);
  atomicAdd(p1 + 1, uu * hv.y);
  atomicAdd(p1 + 2, uu * hv.z);
  atomicAdd(p1 + 3, uu * hv.w);
}

// K5: out = log_softmax( (A0@W2[0] + A1@W2[1])/max(cnt,1) + h@root2 + bias2 )
__global__ __launch_bounds__(256) void k_final(const float* __restrict__ A0,
    const float* __restrict__ A1, const float* __restrict__ h,
    const float* __restrict__ cnt, const float* __restrict__ W2,
    const float* __restrict__ root2, const float* __restrict__ bias2,
    float* __restrict__ out) {
  __shared__ float w20[HID * NC];
  __shared__ float w21[HID * NC];
  __shared__ float r2[HID * NC];
  __shared__ float b2[NC];
  int t = threadIdx.x;
  for (int i = t; i < HID * NC; i += 256) {
    w20[i] = W2[i];
    w21[i] = W2[HID * NC + i];
    r2[i]  = root2[i];
  }
  if (t < NC) b2[t] = bias2[t];
  __syncthreads();
  int wave = t >> 6, l = t & 63;
  int n = blockIdx.x * 4 + wave;
  float a0 = A0[(size_t)n * HID + (l & 15)];
  float a1 = A1[(size_t)n * HID + (l & 15)];
  float hv = h[(size_t)n * HID + (l & 15)];
  float ic = 1.0f / fmaxf(cnt[n], 1.0f);
  int j = (l < NC) ? l : 0;
  float accm = 0.f, accr = 0.f;
#pragma unroll
  for (int k = 0; k < HID; ++k) {
    float a0k = __shfl(a0, k);
    float a1k = __shfl(a1, k);
    float hk  = __shfl(hv, k);
    accm += a0k * w20[k * NC + j] + a1k * w21[k * NC + j];
    accr += hk * r2[k * NC + j];
  }
  float logit = accm * ic + accr + b2[j];
  float mx = (l < NC) ? logit : -INFINITY;
#pragma unroll
  for (int off = 32; off >= 1; off >>= 1) mx = fmaxf(mx, __shfl_xor(mx, off));
  float p = (l < NC) ? expf(logit - mx) : 0.f;
  float sm = p;
#pragma unroll
  for (int off = 32; off >= 1; off >>= 1) sm += __shfl_xor(sm, off);
  if (l < NC) out[(size_t)n * NC + l] = logit - mx - logf(sm);
}

extern "C" void kernel_launch(void* const* d_in, const int* in_sizes, int n_in,
                              void* d_out, int out_size, void* d_ws, size_t ws_size,
                              hipStream_t stream) {
  const float* x     = (const float*)d_in[0];
  const int*   ei    = (const int*)d_in[1];
  const float* ea    = (const float*)d_in[2];
  const float* W1    = (const float*)d_in[3];
  const float* root1 = (const float*)d_in[4];
  const float* bias1 = (const float*)d_in[5];
  const float* W2    = (const float*)d_in[6];
  const float* root2 = (const float*)d_in[7];
  const float* bias2 = (const float*)d_in[8];
  float* out = (float*)d_out;
  float* ws  = (float*)d_ws;

  const size_t NH = (size_t)NN * HID;   // 1.6M floats
  float* X0  = ws;            // later reused as A0
  float* D   = ws + NH;       // later reused as A1
  float* XR  = ws + 2 * NH;
  float* C   = ws + 3 * NH;   // agg1 -> h (in place)
  float* cnt = ws + 4 * NH;   // NN floats

  hipMemsetAsync(C, 0, NH * sizeof(float), stream);
  hipMemsetAsync(cnt, 0, NN * sizeof(float), stream);

  k_gemm1<<<NN / 16, 256, 0, stream>>>(x, W1, root1, bias1, X0, D, XR);
  k_edge1<<<(NE * 4) / 256, 256, 0, stream>>>(ei, ea, X0, D, C, cnt);
  k_node1<<<(NN * HID / 4 + 255) / 256, 256, 0, stream>>>(C, XR, cnt);

  hipMemsetAsync(X0, 0, NH * sizeof(float), stream);  // A0
  hipMemsetAsync(D, 0, NH * sizeof(float), stream);   // A1
  k_edge2<<<(NE * 4) / 256, 256, 0, stream>>>(ei, ea, C, X0, D);
  k_final<<<NN / 4, 256, 0, stream>>>(X0, D, C, cnt, W2, root2, bias2, out);
}

// Round 2
// 730.916 us; speedup vs baseline: 3.0752x; 3.0752x over previous
//
#include <hip/hip_runtime.h>
#include <cstddef>

#define NN 100000
#define NE 3200000
#define FIN 128
#define HID 16
#define NC 40
#define NB_SCAN ((NN + 255) / 256)   // 391

// K1: X0 = x@W1[0]; D = x@W1[1] - X0; XR = x@root1 + bias1   (per node, 48 outputs)
__global__ __launch_bounds__(256) void k_gemm1(const float* __restrict__ x,
    const float* __restrict__ W1, const float* __restrict__ root1,
    const float* __restrict__ bias1,
    float* __restrict__ X0, float* __restrict__ D, float* __restrict__ XR) {
  __shared__ float wT[48][132];   // transposed weights: wT[j][k]
  __shared__ float xs[16][132];   // 16 node rows, padded stride
  int t = threadIdx.x;
  for (int i = t; i < 48 * FIN; i += 256) {
    int j = i >> 7, k = i & 127;
    float v;
    if (j < 16)      v = W1[k * 16 + j];
    else if (j < 32) v = W1[2048 + k * 16 + (j - 16)];
    else             v = root1[k * 16 + (j - 32)];
    wT[j][k] = v;
  }
  const float4* x4 = (const float4*)(x + (size_t)blockIdx.x * 16 * FIN);
  for (int i = t; i < 16 * FIN / 4; i += 256) {
    float4 v = x4[i];
    int r = i >> 5, c = (i & 31) << 2;
    *(float4*)&xs[r][c] = v;
  }
  __syncthreads();
  int nl = t >> 4, j = t & 15;
  float a0 = 0.f, a1 = 0.f, ar = 0.f;
#pragma unroll
  for (int k = 0; k < FIN; k += 4) {
    float4 xv = *(const float4*)&xs[nl][k];
    float4 w0 = *(const float4*)&wT[j][k];
    float4 w1 = *(const float4*)&wT[j + 16][k];
    float4 wr = *(const float4*)&wT[j + 32][k];
    a0 += xv.x * w0.x + xv.y * w0.y + xv.z * w0.z + xv.w * w0.w;
    a1 += xv.x * w1.x + xv.y * w1.y + xv.z * w1.z + xv.w * w1.w;
    ar += xv.x * wr.x + xv.y * wr.y + xv.z * wr.z + xv.w * wr.w;
  }
  size_t idx = (size_t)(blockIdx.x * 16 + nl) * HID + j;
  X0[idx] = a0;
  D[idx]  = a1 - a0;
  XR[idx] = ar + bias1[j];
}

// Histogram of dst
__global__ __launch_bounds__(256) void k_hist(const int* __restrict__ ei,
                                              int* __restrict__ cnt) {
  int e = blockIdx.x * 256 + threadIdx.x;
  if (e >= NE) return;
  atomicAdd(&cnt[ei[NE + e]], 1);
}

// Exclusive scan, 3 kernels
__global__ __launch_bounds__(256) void k_scan1(const int* __restrict__ cnt,
    int* __restrict__ off, int* __restrict__ bsum) {
  __shared__ int s[256];
  int t = threadIdx.x, i = blockIdx.x * 256 + t;
  int v = (i < NN) ? cnt[i] : 0;
  s[t] = v;
  __syncthreads();
  for (int st = 1; st < 256; st <<= 1) {
    int tmp = (t >= st) ? s[t - st] : 0;
    __syncthreads();
    s[t] += tmp;
    __syncthreads();
  }
  if (i < NN) off[i] = s[t] - v;          // exclusive (block-local)
  if (t == 255) bsum[blockIdx.x] = s[255];
}

__global__ __launch_bounds__(512) void k_scan2(int* __restrict__ bsum) {
  __shared__ int s[512];
  int t = threadIdx.x;
  int v = (t < NB_SCAN) ? bsum[t] : 0;
  s[t] = v;
  __syncthreads();
  for (int st = 1; st < 512; st <<= 1) {
    int tmp = (t >= st) ? s[t - st] : 0;
    __syncthreads();
    s[t] += tmp;
    __syncthreads();
  }
  if (t < NB_SCAN) bsum[t] = s[t] - v;    // exclusive over block totals
}

__global__ __launch_bounds__(256) void k_scan3(int* __restrict__ off,
                                               const int* __restrict__ bsum) {
  int i = blockIdx.x * 256 + threadIdx.x;
  if (i < NN) off[i] += bsum[blockIdx.x];
}

// Scatter edges into CSR slots. Mutates off: afterwards off[d] == orig_off[d+1].
__global__ __launch_bounds__(256) void k_scatter(const int* __restrict__ ei,
    const float* __restrict__ ea, int* __restrict__ off, int2* __restrict__ sedge) {
  int e = blockIdx.x * 256 + threadIdx.x;
  if (e >= NE) return;
  int s = ei[e], d = ei[NE + e];
  int pos = atomicAdd(&off[d], 1);
  sedge[pos] = make_int2(s, __float_as_int(ea[e]));
}

// Pull pass 1 fused with mean + root + ELU:  H[n] = elu(mean_e(X0[s]+u*D[s]) + XR[n])
__global__ __launch_bounds__(256) void k_pull1(const int* __restrict__ off,
    const int2* __restrict__ sedge, const float* __restrict__ X0,
    const float* __restrict__ D, const float* __restrict__ XR,
    float* __restrict__ H) {
  int tid = blockIdx.x * 256 + threadIdx.x;
  int n = tid >> 2, c = tid & 3;
  if (n >= NN) return;
  int start = (n == 0) ? 0 : off[n - 1];
  int end = off[n];
  float4 acc = make_float4(0.f, 0.f, 0.f, 0.f);
  for (int i = start; i < end; ++i) {
    int2 se = sedge[i];
    int s = se.x;
    float u = __int_as_float(se.y);
    float4 x0 = *(const float4*)(X0 + (size_t)s * HID + c * 4);
    float4 dd = *(const float4*)(D  + (size_t)s * HID + c * 4);
    acc.x += x0.x + u * dd.x;
    acc.y += x0.y + u * dd.y;
    acc.z += x0.z + u * dd.z;
    acc.w += x0.w + u * dd.w;
  }
  float ic = 1.0f / fmaxf((float)(end - start), 1.0f);
  float4 r = *(const float4*)(XR + (size_t)n * HID + c * 4);
  float4 h;
  h.x = acc.x * ic + r.x;
  h.y = acc.y * ic + r.y;
  h.z = acc.z * ic + r.z;
  h.w = acc.w * ic + r.w;
  h.x = h.x > 0.f ? h.x : expm1f(h.x);
  h.y = h.y > 0.f ? h.y : expm1f(h.y);
  h.z = h.z > 0.f ? h.z : expm1f(h.z);
  h.w = h.w > 0.f ? h.w : expm1f(h.w);
  *(float4*)(H + (size_t)n * HID + c * 4) = h;
}

// Pull pass 2: A0[n] = sum (1-u)*H[s];  A1[n] = sum u*H[s]
__global__ __launch_bounds__(256) void k_pull2(const int* __restrict__ off,
    const int2* __restrict__ sedge, const float* __restrict__ H,
    float* __restrict__ A0, float* __restrict__ A1) {
  int tid = blockIdx.x * 256 + threadIdx.x;
  int n = tid >> 2, c = tid & 3;
  if (n >= NN) return;
  int start = (n == 0) ? 0 : off[n - 1];
  int end = off[n];
  float4 a0 = make_float4(0.f, 0.f, 0.f, 0.f);
  float4 a1 = make_float4(0.f, 0.f, 0.f, 0.f);
  for (int i = start; i < end; ++i) {
    int2 se = sedge[i];
    int s = se.x;
    float u = __int_as_float(se.y);
    float4 hv = *(const float4*)(H + (size_t)s * HID + c * 4);
    a0.x += hv.x - u * hv.x;
    a0.y += hv.y - u * hv.y;
    a0.z += hv.z - u * hv.z;
    a0.w += hv.w - u * hv.w;
    a1.x += u * hv.x;
    a1.y += u * hv.y;
    a1.z += u * hv.z;
    a1.w += u * hv.w;
  }
  *(float4*)(A0 + (size_t)n * HID + c * 4) = a0;
  *(float4*)(A1 + (size_t)n * HID + c * 4) = a1;
}

// K5: out = log_softmax( (A0@W2[0] + A1@W2[1])/max(deg,1) + H@root2 + bias2 )
__global__ __launch_bounds__(256) void k_final(const float* __restrict__ A0,
    const float* __restrict__ A1, const float* __restrict__ H,
    const int* __restrict__ off, const float* __restrict__ W2,
    const float* __restrict__ root2, const float* __restrict__ bias2,
    float* __restrict__ out) {
  __shared__ float w20[HID * NC];
  __shared__ float w21[HID * NC];
  __shared__ float r2[HID * NC];
  __shared__ float b2[NC];
  int t = threadIdx.x;
  for (int i = t; i < HID * NC; i += 256) {
    w20[i] = W2[i];
    w21[i] = W2[HID * NC + i];
    r2[i]  = root2[i];
  }
  if (t < NC) b2[t] = bias2[t];
  __syncthreads();
  int wave = t >> 6, l = t & 63;
  int n = blockIdx.x * 4 + wave;
  float a0 = A0[(size_t)n * HID + (l & 15)];
  float a1 = A1[(size_t)n * HID + (l & 15)];
  float hv = H[(size_t)n * HID + (l & 15)];
  int deg = off[n] - ((n == 0) ? 0 : off[n - 1]);
  float ic = 1.0f / fmaxf((float)deg, 1.0f);
  int j = (l < NC) ? l : 0;
  float accm = 0.f, accr = 0.f;
#pragma unroll
  for (int k = 0; k < HID; ++k) {
    float a0k = __shfl(a0, k);
    float a1k = __shfl(a1, k);
    float hk  = __shfl(hv, k);
    accm += a0k * w20[k * NC + j] + a1k * w21[k * NC + j];
    accr += hk * r2[k * NC + j];
  }
  float logit = accm * ic + accr + b2[j];
  float mx = (l < NC) ? logit : -INFINITY;
#pragma unroll
  for (int off2 = 32; off2 >= 1; off2 >>= 1) mx = fmaxf(mx, __shfl_xor(mx, off2));
  float p = (l < NC) ? expf(logit - mx) : 0.f;
  float sm = p;
#pragma unroll
  for (int off2 = 32; off2 >= 1; off2 >>= 1) sm += __shfl_xor(sm, off2);
  if (l < NC) out[(size_t)n * NC + l] = logit - mx - logf(sm);
}

extern "C" void kernel_launch(void* const* d_in, const int* in_sizes, int n_in,
                              void* d_out, int out_size, void* d_ws, size_t ws_size,
                              hipStream_t stream) {
  const float* x     = (const float*)d_in[0];
  const int*   ei    = (const int*)d_in[1];
  const float* ea    = (const float*)d_in[2];
  const float* W1    = (const float*)d_in[3];
  const float* root1 = (const float*)d_in[4];
  const float* bias1 = (const float*)d_in[5];
  const float* W2    = (const float*)d_in[6];
  const float* root2 = (const float*)d_in[7];
  const float* bias2 = (const float*)d_in[8];
  float* out = (float*)d_out;
  float* ws  = (float*)d_ws;

  const size_t NH = (size_t)NN * HID;   // 1.6M floats
  float* X0  = ws;                      // later reused as A0
  float* D   = ws + NH;                 // later reused as A1
  float* XR  = ws + 2 * NH;
  float* H   = ws + 3 * NH;
  int*   cnt  = (int*)(ws + 4 * NH);
  int*   off  = cnt + NN;
  int*   bsum = off + NN;
  int2*  sedge = (int2*)(bsum + 512);   // NE int2 (25.6 MB)

  hipMemsetAsync(cnt, 0, NN * sizeof(int), stream);

  k_gemm1<<<NN / 16, 256, 0, stream>>>(x, W1, root1, bias1, X0, D, XR);
  k_hist<<<(NE + 255) / 256, 256, 0, stream>>>(ei, cnt);
  k_scan1<<<NB_SCAN, 256, 0, stream>>>(cnt, off, bsum);
  k_scan2<<<1, 512, 0, stream>>>(bsum);
  k_scan3<<<NB_SCAN, 256, 0, stream>>>(off, bsum);
  k_scatter<<<(NE + 255) / 256, 256, 0, stream>>>(ei, ea, off, sedge);
  k_pull1<<<(NN * 4 + 255) / 256, 256, 0, stream>>>(off, sedge, X0, D, XR, H);
  k_pull2<<<(NN * 4 + 255) / 256, 256, 0, stream>>>(off, sedge, H, X0, D);
  k_final<<<NN / 4, 256, 0, stream>>>(X0, D, H, off, W2, root2, bias2, out);
}

// Round 3
// 448.485 us; speedup vs baseline: 5.0119x; 1.6297x over previous
//
#include <hip/hip_runtime.h>
#include <cstddef>

#define NN 100000
#define NE 3200000
#define FIN 128
#define HID 16
#define NC 40
#define NBUK 196                 // ceil(100000 / 512) node-range buckets
#define CHUNK 4096               // edges per block in bucketing passes
#define NBLK_BKT ((NE + CHUNK - 1) / CHUNK)   // 782

// ---------- CSR build: bucketed counting sort (atomic-light) ----------

// Pass A: per-block LDS histogram of bucket(dst) -> global bucket counts
__global__ __launch_bounds__(256) void k_bcount(const int* __restrict__ ei,
                                                int* __restrict__ bcnt) {
  __shared__ int h[NBUK];
  int t = threadIdx.x;
  for (int i = t; i < NBUK; i += 256) h[i] = 0;
  __syncthreads();
  int base = blockIdx.x * CHUNK;
#pragma unroll
  for (int i = 0; i < 16; ++i) {
    int e = base + i * 256 + t;
    if (e < NE) atomicAdd(&h[ei[NE + e] >> 9], 1);
  }
  __syncthreads();
  for (int i = t; i < NBUK; i += 256)
    if (h[i]) atomicAdd(&bcnt[i], h[i]);
}

// Pass B: exclusive scan of 196 bucket counts -> bases + cursors
__global__ __launch_bounds__(256) void k_bscan(const int* __restrict__ bcnt,
    int* __restrict__ bbase, int* __restrict__ bcur) {
  __shared__ int scn[256];
  int t = threadIdx.x;
  int v = (t < NBUK) ? bcnt[t] : 0;
  scn[t] = v;
  __syncthreads();
  for (int st = 1; st < 256; st <<= 1) {
    int tmp = (t >= st) ? scn[t - st] : 0;
    __syncthreads();
    scn[t] += tmp;
    __syncthreads();
  }
  if (t < NBUK) { int ex = scn[t] - v; bbase[t] = ex; bcur[t] = ex; }
  if (t == NBUK - 1) bbase[NBUK] = scn[t];
}

// Pass C: block-local counting sort into bucket streams.
// Record: .x = (dst&511)<<17 | src   (src < 2^17), .y = bits(u)
__global__ __launch_bounds__(256) void k_bucketize(const int* __restrict__ ei,
    const float* __restrict__ ea, int* __restrict__ bcur,
    int2* __restrict__ bstream) {
  __shared__ int lh[NBUK];
  __shared__ int lbase[NBUK];
  __shared__ int gb[NBUK];
  __shared__ int scn[256];
  __shared__ int meta[CHUNK];
  __shared__ int uval[CHUNK];
  __shared__ unsigned char sbkt[CHUNK];
  int t = threadIdx.x;
  for (int i = t; i < NBUK; i += 256) lh[i] = 0;
  __syncthreads();
  int base = blockIdx.x * CHUNK;
  int rk[16], bk[16], mt[16], uv[16];
#pragma unroll
  for (int i = 0; i < 16; ++i) {
    int e = base + i * 256 + t;
    if (e < NE) {
      int d = ei[NE + e], sv = ei[e];
      int b = d >> 9;
      rk[i] = atomicAdd(&lh[b], 1);
      bk[i] = b;
      mt[i] = ((d & 511) << 17) | sv;
      uv[i] = __float_as_int(ea[e]);
    } else bk[i] = -1;
  }
  __syncthreads();
  int v = (t < NBUK) ? lh[t] : 0;
  scn[t] = v;
  __syncthreads();
  for (int st = 1; st < 256; st <<= 1) {
    int tmp = (t >= st) ? scn[t - st] : 0;
    __syncthreads();
    scn[t] += tmp;
    __syncthreads();
  }
  if (t < NBUK) lbase[t] = scn[t] - v;
  int total = scn[255];
  __syncthreads();
  if (t < NBUK && lh[t] > 0) gb[t] = atomicAdd(&bcur[t], lh[t]);
  __syncthreads();
#pragma unroll
  for (int i = 0; i < 16; ++i) {
    if (bk[i] >= 0) {
      int p = lbase[bk[i]] + rk[i];
      meta[p] = mt[i];
      uval[p] = uv[i];
      sbkt[p] = (unsigned char)bk[i];
    }
  }
  __syncthreads();
  for (int s = t; s < total; s += 256) {
    int b = sbkt[s];
    bstream[gb[b] + (s - lbase[b])] = make_int2(meta[s], uval[s]);
  }
}

// Pass D: one block per bucket -> exact CSR (off[] + sedge) via LDS atomics
__global__ __launch_bounds__(512) void k_csr(const int2* __restrict__ bstream,
    const int* __restrict__ bbase, int* __restrict__ off,
    int2* __restrict__ sedge) {
  __shared__ int cnt[512];
  __shared__ int scn[512];
  __shared__ int cur[512];
  int b = blockIdx.x, t = threadIdx.x;
  int s0 = bbase[b], s1 = bbase[b + 1];
  cnt[t] = 0;
  __syncthreads();
  for (int i = s0 + t; i < s1; i += 512)
    atomicAdd(&cnt[bstream[i].x >> 17], 1);
  __syncthreads();
  int v = cnt[t];
  scn[t] = v;
  __syncthreads();
  for (int st = 1; st < 512; st <<= 1) {
    int tmp = (t >= st) ? scn[t - st] : 0;
    __syncthreads();
    scn[t] += tmp;
    __syncthreads();
  }
  int n = (b << 9) + t;
  if (n < NN) off[n] = s0 + scn[t];          // inclusive row-end
  cur[t] = s0 + scn[t] - v;                  // row start cursor
  __syncthreads();
  for (int i = s0 + t; i < s1; i += 512) {
    int2 r = bstream[i];
    int local = r.x >> 17;
    int pos = atomicAdd(&cur[local], 1);
    sedge[pos] = make_int2(r.x & 131071, r.y);
  }
}

// ---------- dense / pull kernels (unchanged from round 2) ----------

__global__ __launch_bounds__(256) void k_gemm1(const float* __restrict__ x,
    const float* __restrict__ W1, const float* __restrict__ root1,
    const float* __restrict__ bias1,
    float* __restrict__ X0, float* __restrict__ D, float* __restrict__ XR) {
  __shared__ float wT[48][132];
  __shared__ float xs[16][132];
  int t = threadIdx.x;
  for (int i = t; i < 48 * FIN; i += 256) {
    int j = i >> 7, k = i & 127;
    float v;
    if (j < 16)      v = W1[k * 16 + j];
    else if (j < 32) v = W1[2048 + k * 16 + (j - 16)];
    else             v = root1[k * 16 + (j - 32)];
    wT[j][k] = v;
  }
  const float4* x4 = (const float4*)(x + (size_t)blockIdx.x * 16 * FIN);
  for (int i = t; i < 16 * FIN / 4; i += 256) {
    float4 v = x4[i];
    int r = i >> 5, c = (i & 31) << 2;
    *(float4*)&xs[r][c] = v;
  }
  __syncthreads();
  int nl = t >> 4, j = t & 15;
  float a0 = 0.f, a1 = 0.f, ar = 0.f;
#pragma unroll
  for (int k = 0; k < FIN; k += 4) {
    float4 xv = *(const float4*)&xs[nl][k];
    float4 w0 = *(const float4*)&wT[j][k];
    float4 w1 = *(const float4*)&wT[j + 16][k];
    float4 wr = *(const float4*)&wT[j + 32][k];
    a0 += xv.x * w0.x + xv.y * w0.y + xv.z * w0.z + xv.w * w0.w;
    a1 += xv.x * w1.x + xv.y * w1.y + xv.z * w1.z + xv.w * w1.w;
    ar += xv.x * wr.x + xv.y * wr.y + xv.z * wr.z + xv.w * wr.w;
  }
  size_t idx = (size_t)(blockIdx.x * 16 + nl) * HID + j;
  X0[idx] = a0;
  D[idx]  = a1 - a0;
  XR[idx] = ar + bias1[j];
}

__global__ __launch_bounds__(256) void k_pull1(const int* __restrict__ off,
    const int2* __restrict__ sedge, const float* __restrict__ X0,
    const float* __restrict__ D, const float* __restrict__ XR,
    float* __restrict__ H) {
  int tid = blockIdx.x * 256 + threadIdx.x;
  int n = tid >> 2, c = tid & 3;
  if (n >= NN) return;
  int start = (n == 0) ? 0 : off[n - 1];
  int end = off[n];
  float4 acc = make_float4(0.f, 0.f, 0.f, 0.f);
  for (int i = start; i < end; ++i) {
    int2 se = sedge[i];
    int s = se.x;
    float u = __int_as_float(se.y);
    float4 x0 = *(const float4*)(X0 + (size_t)s * HID + c * 4);
    float4 dd = *(const float4*)(D  + (size_t)s * HID + c * 4);
    acc.x += x0.x + u * dd.x;
    acc.y += x0.y + u * dd.y;
    acc.z += x0.z + u * dd.z;
    acc.w += x0.w + u * dd.w;
  }
  float ic = 1.0f / fmaxf((float)(end - start), 1.0f);
  float4 r = *(const float4*)(XR + (size_t)n * HID + c * 4);
  float4 h;
  h.x = acc.x * ic + r.x;
  h.y = acc.y * ic + r.y;
  h.z = acc.z * ic + r.z;
  h.w = acc.w * ic + r.w;
  h.x = h.x > 0.f ? h.x : expm1f(h.x);
  h.y = h.y > 0.f ? h.y : expm1f(h.y);
  h.z = h.z > 0.f ? h.z : expm1f(h.z);
  h.w = h.w > 0.f ? h.w : expm1f(h.w);
  *(float4*)(H + (size_t)n * HID + c * 4) = h;
}

__global__ __launch_bounds__(256) void k_pull2(const int* __restrict__ off,
    const int2* __restrict__ sedge, const float* __restrict__ H,
    float* __restrict__ A0, float* __restrict__ A1) {
  int tid = blockIdx.x * 256 + threadIdx.x;
  int n = tid >> 2, c = tid & 3;
  if (n >= NN) return;
  int start = (n == 0) ? 0 : off[n - 1];
  int end = off[n];
  float4 a0 = make_float4(0.f, 0.f, 0.f, 0.f);
  float4 a1 = make_float4(0.f, 0.f, 0.f, 0.f);
  for (int i = start; i < end; ++i) {
    int2 se = sedge[i];
    int s = se.x;
    float u = __int_as_float(se.y);
    float4 hv = *(const float4*)(H + (size_t)s * HID + c * 4);
    a0.x += hv.x - u * hv.x;
    a0.y += hv.y - u * hv.y;
    a0.z += hv.z - u * hv.z;
    a0.w += hv.w - u * hv.w;
    a1.x += u * hv.x;
    a1.y += u * hv.y;
    a1.z += u * hv.z;
    a1.w += u * hv.w;
  }
  *(float4*)(A0 + (size_t)n * HID + c * 4) = a0;
  *(float4*)(A1 + (size_t)n * HID + c * 4) = a1;
}

__global__ __launch_bounds__(256) void k_final(const float* __restrict__ A0,
    const float* __restrict__ A1, const float* __restrict__ H,
    const int* __restrict__ off, const float* __restrict__ W2,
    const float* __restrict__ root2, const float* __restrict__ bias2,
    float* __restrict__ out) {
  __shared__ float w20[HID * NC];
  __shared__ float w21[HID * NC];
  __shared__ float r2[HID * NC];
  __shared__ float b2[NC];
  int t = threadIdx.x;
  for (int i = t; i < HID * NC; i += 256) {
    w20[i] = W2[i];
    w21[i] = W2[HID * NC + i];
    r2[i]  = root2[i];
  }
  if (t < NC) b2[t] = bias2[t];
  __syncthreads();
  int wave = t >> 6, l = t & 63;
  int n = blockIdx.x * 4 + wave;
  float a0 = A0[(size_t)n * HID + (l & 15)];
  float a1 = A1[(size_t)n * HID + (l & 15)];
  float hv = H[(size_t)n * HID + (l & 15)];
  int deg = off[n] - ((n == 0) ? 0 : off[n - 1]);
  float ic = 1.0f / fmaxf((float)deg, 1.0f);
  int j = (l < NC) ? l : 0;
  float accm = 0.f, accr = 0.f;
#pragma unroll
  for (int k = 0; k < HID; ++k) {
    float a0k = __shfl(a0, k);
    float a1k = __shfl(a1, k);
    float hk  = __shfl(hv, k);
    accm += a0k * w20[k * NC + j] + a1k * w21[k * NC + j];
    accr += hk * r2[k * NC + j];
  }
  float logit = accm * ic + accr + b2[j];
  float mx = (l < NC) ? logit : -INFINITY;
#pragma unroll
  for (int off2 = 32; off2 >= 1; off2 >>= 1) mx = fmaxf(mx, __shfl_xor(mx, off2));
  float p = (l < NC) ? expf(logit - mx) : 0.f;
  float sm = p;
#pragma unroll
  for (int off2 = 32; off2 >= 1; off2 >>= 1) sm += __shfl_xor(sm, off2);
  if (l < NC) out[(size_t)n * NC + l] = logit - mx - logf(sm);
}

extern "C" void kernel_launch(void* const* d_in, const int* in_sizes, int n_in,
                              void* d_out, int out_size, void* d_ws, size_t ws_size,
                              hipStream_t stream) {
  const float* x     = (const float*)d_in[0];
  const int*   ei    = (const int*)d_in[1];
  const float* ea    = (const float*)d_in[2];
  const float* W1    = (const float*)d_in[3];
  const float* root1 = (const float*)d_in[4];
  const float* bias1 = (const float*)d_in[5];
  const float* W2    = (const float*)d_in[6];
  const float* root2 = (const float*)d_in[7];
  const float* bias2 = (const float*)d_in[8];
  float* out = (float*)d_out;
  float* ws  = (float*)d_ws;

  const size_t NH = (size_t)NN * HID;   // 1.6M floats
  // Node tables (25.6 MB). During CSR build this same region is bstream
  // (NE int2 = 25.6 MB, exactly 4*NH floats) — dead before k_gemm1 writes it.
  float* X0  = ws;                      // later reused as A0
  float* D   = ws + NH;                 // later reused as A1
  float* XR  = ws + 2 * NH;
  float* H   = ws + 3 * NH;
  int2*  bstream = (int2*)ws;

  int2*  sedge = (int2*)(ws + 4 * NH);          // NE int2 (25.6 MB), 8B-aligned
  int*   off   = (int*)(sedge + NE);            // NN
  int*   bcnt  = off + NN;                      // NBUK
  int*   bbase = bcnt + NBUK;                   // NBUK+1
  int*   bcur  = bbase + NBUK + 1;              // NBUK

  hipMemsetAsync(bcnt, 0, NBUK * sizeof(int), stream);

  // CSR build first (bstream aliases node tables)
  k_bcount<<<NBLK_BKT, 256, 0, stream>>>(ei, bcnt);
  k_bscan<<<1, 256, 0, stream>>>(bcnt, bbase, bcur);
  k_bucketize<<<NBLK_BKT, 256, 0, stream>>>(ei, ea, bcur, bstream);
  k_csr<<<NBUK, 512, 0, stream>>>(bstream, bbase, off, sedge);

  // Dense + pulls
  k_gemm1<<<NN / 16, 256, 0, stream>>>(x, W1, root1, bias1, X0, D, XR);
  k_pull1<<<(NN * 4 + 255) / 256, 256, 0, stream>>>(off, sedge, X0, D, XR, H);
  k_pull2<<<(NN * 4 + 255) / 256, 256, 0, stream>>>(off, sedge, H, X0, D);
  k_final<<<NN / 4, 256, 0, stream>>>(X0, D, H, off, W2, root2, bias2, out);
}

// Round 4
// 361.016 us; speedup vs baseline: 6.2262x; 1.2423x over previous
//
#include <hip/hip_runtime.h>
#include <cstddef>

#define NN 100000
#define NE 3200000
#define FIN 128
#define HID 16
#define NC 40
#define NBUK 196                 // ceil(100000 / 512) node-range buckets
#define CHUNK 4096               // edges per block in bucketing passes
#define NBLK_BKT ((NE + CHUNK - 1) / CHUNK)   // 782

// ---- bf16 helpers (RNE pack, cheap unpack) ----
__device__ __forceinline__ unsigned bf16rne(float f) {
  unsigned u = __float_as_uint(f);
  return (u + 0x7fffu + ((u >> 16) & 1u)) >> 16;
}
__device__ __forceinline__ unsigned bfpack(float lo, float hi) {
  return bf16rne(lo) | (bf16rne(hi) << 16);
}
__device__ __forceinline__ float bflo(unsigned w) { return __uint_as_float(w << 16); }
__device__ __forceinline__ float bfhi(unsigned w) { return __uint_as_float(w & 0xffff0000u); }

// ---------- CSR build: bucketed counting sort (atomic-light) ----------

__global__ __launch_bounds__(256) void k_bcount(const int* __restrict__ ei,
                                                int* __restrict__ bcnt) {
  __shared__ int h[NBUK];
  int t = threadIdx.x;
  for (int i = t; i < NBUK; i += 256) h[i] = 0;
  __syncthreads();
  int base = blockIdx.x * CHUNK;
#pragma unroll
  for (int i = 0; i < 16; ++i) {
    int e = base + i * 256 + t;
    if (e < NE) atomicAdd(&h[ei[NE + e] >> 9], 1);
  }
  __syncthreads();
  for (int i = t; i < NBUK; i += 256)
    if (h[i]) atomicAdd(&bcnt[i], h[i]);
}

__global__ __launch_bounds__(256) void k_bscan(const int* __restrict__ bcnt,
    int* __restrict__ bbase, int* __restrict__ bcur) {
  __shared__ int scn[256];
  int t = threadIdx.x;
  int v = (t < NBUK) ? bcnt[t] : 0;
  scn[t] = v;
  __syncthreads();
  for (int st = 1; st < 256; st <<= 1) {
    int tmp = (t >= st) ? scn[t - st] : 0;
    __syncthreads();
    scn[t] += tmp;
    __syncthreads();
  }
  if (t < NBUK) { int ex = scn[t] - v; bbase[t] = ex; bcur[t] = ex; }
  if (t == NBUK - 1) bbase[NBUK] = scn[t];
}

// Record: .x = (dst&511)<<17 | src   (src < 2^17), .y = bits(u)
__global__ __launch_bounds__(256) void k_bucketize(const int* __restrict__ ei,
    const float* __restrict__ ea, int* __restrict__ bcur,
    int2* __restrict__ bstream) {
  __shared__ int lh[NBUK];
  __shared__ int lbase[NBUK];
  __shared__ int gb[NBUK];
  __shared__ int scn[256];
  __shared__ int meta[CHUNK];
  __shared__ int uval[CHUNK];
  __shared__ unsigned char sbkt[CHUNK];
  int t = threadIdx.x;
  for (int i = t; i < NBUK; i += 256) lh[i] = 0;
  __syncthreads();
  int base = blockIdx.x * CHUNK;
  int rk[16], bk[16], mt[16], uv[16];
#pragma unroll
  for (int i = 0; i < 16; ++i) {
    int e = base + i * 256 + t;
    if (e < NE) {
      int d = ei[NE + e], sv = ei[e];
      int b = d >> 9;
      rk[i] = atomicAdd(&lh[b], 1);
      bk[i] = b;
      mt[i] = ((d & 511) << 17) | sv;
      uv[i] = __float_as_int(ea[e]);
    } else bk[i] = -1;
  }
  __syncthreads();
  int v = (t < NBUK) ? lh[t] : 0;
  scn[t] = v;
  __syncthreads();
  for (int st = 1; st < 256; st <<= 1) {
    int tmp = (t >= st) ? scn[t - st] : 0;
    __syncthreads();
    scn[t] += tmp;
    __syncthreads();
  }
  if (t < NBUK) lbase[t] = scn[t] - v;
  int total = scn[255];
  __syncthreads();
  if (t < NBUK && lh[t] > 0) gb[t] = atomicAdd(&bcur[t], lh[t]);
  __syncthreads();
#pragma unroll
  for (int i = 0; i < 16; ++i) {
    if (bk[i] >= 0) {
      int p = lbase[bk[i]] + rk[i];
      meta[p] = mt[i];
      uval[p] = uv[i];
      sbkt[p] = (unsigned char)bk[i];
    }
  }
  __syncthreads();
  for (int s = t; s < total; s += 256) {
    int b = sbkt[s];
    bstream[gb[b] + (s - lbase[b])] = make_int2(meta[s], uval[s]);
  }
}

// Pass D: one block per bucket -> off[] + packed sedge (src | u15<<17)
__global__ __launch_bounds__(512) void k_csr(const int2* __restrict__ bstream,
    const int* __restrict__ bbase, int* __restrict__ off,
    unsigned* __restrict__ sedge) {
  __shared__ int cnt[512];
  __shared__ int scn[512];
  __shared__ int cur[512];
  int b = blockIdx.x, t = threadIdx.x;
  int s0 = bbase[b], s1 = bbase[b + 1];
  cnt[t] = 0;
  __syncthreads();
  for (int i = s0 + t; i < s1; i += 512)
    atomicAdd(&cnt[bstream[i].x >> 17], 1);
  __syncthreads();
  int v = cnt[t];
  scn[t] = v;
  __syncthreads();
  for (int st = 1; st < 512; st <<= 1) {
    int tmp = (t >= st) ? scn[t - st] : 0;
    __syncthreads();
    scn[t] += tmp;
    __syncthreads();
  }
  int n = (b << 9) + t;
  if (n < NN) off[n] = s0 + scn[t];          // inclusive row-end
  cur[t] = s0 + scn[t] - v;                  // row start cursor
  __syncthreads();
  for (int i = s0 + t; i < s1; i += 512) {
    int2 r = bstream[i];
    int local = r.x >> 17;
    int pos = atomicAdd(&cur[local], 1);
    unsigned u15 = (unsigned)__float2int_rn(__int_as_float(r.y) * 32767.0f);
    sedge[pos] = (unsigned)(r.x & 131071) | (u15 << 17);
  }
}

// ---------- dense / pull kernels ----------

// K1: XD[n][j] = pack(X0[n][j], X1[n][j]-X0[n][j]) bf16; XR = x@root1 + bias1 (f32)
__global__ __launch_bounds__(256) void k_gemm1(const float* __restrict__ x,
    const float* __restrict__ W1, const float* __restrict__ root1,
    const float* __restrict__ bias1,
    unsigned* __restrict__ XD, float* __restrict__ XR) {
  __shared__ float wT[48][132];
  __shared__ float xs[16][132];
  int t = threadIdx.x;
  for (int i = t; i < 48 * FIN; i += 256) {
    int j = i >> 7, k = i & 127;
    float v;
    if (j < 16)      v = W1[k * 16 + j];
    else if (j < 32) v = W1[2048 + k * 16 + (j - 16)];
    else             v = root1[k * 16 + (j - 32)];
    wT[j][k] = v;
  }
  const float4* x4 = (const float4*)(x + (size_t)blockIdx.x * 16 * FIN);
  for (int i = t; i < 16 * FIN / 4; i += 256) {
    float4 v = x4[i];
    int r = i >> 5, c = (i & 31) << 2;
    *(float4*)&xs[r][c] = v;
  }
  __syncthreads();
  int nl = t >> 4, j = t & 15;
  float a0 = 0.f, a1 = 0.f, ar = 0.f;
#pragma unroll
  for (int k = 0; k < FIN; k += 4) {
    float4 xv = *(const float4*)&xs[nl][k];
    float4 w0 = *(const float4*)&wT[j][k];
    float4 w1 = *(const float4*)&wT[j + 16][k];
    float4 wr = *(const float4*)&wT[j + 32][k];
    a0 += xv.x * w0.x + xv.y * w0.y + xv.z * w0.z + xv.w * w0.w;
    a1 += xv.x * w1.x + xv.y * w1.y + xv.z * w1.z + xv.w * w1.w;
    ar += xv.x * wr.x + xv.y * wr.y + xv.z * wr.z + xv.w * wr.w;
  }
  size_t idx = (size_t)(blockIdx.x * 16 + nl) * HID + j;
  XD[idx] = bfpack(a0, a1 - a0);
  XR[idx] = ar + bias1[j];
}

// Pull pass 1:  Hb[n] = bf16(elu(mean_e(X0[s]+u*D[s]) + XR[n]))
__global__ __launch_bounds__(256) void k_pull1(const int* __restrict__ off,
    const unsigned* __restrict__ sedge, const unsigned* __restrict__ XD,
    const float* __restrict__ XR, unsigned* __restrict__ Hb) {
  int tid = blockIdx.x * 256 + threadIdx.x;
  int n = tid >> 2, c = tid & 3;
  if (n >= NN) return;
  int start = (n == 0) ? 0 : off[n - 1];
  int end = off[n];
  float4 acc = make_float4(0.f, 0.f, 0.f, 0.f);
  for (int i = start; i < end; ++i) {
    unsigned se = sedge[i];
    int s = se & 131071u;
    float u = (float)(se >> 17) * (1.0f / 32767.0f);
    uint4 w = *(const uint4*)(XD + (size_t)s * HID + c * 4);
    acc.x += bflo(w.x) + u * bfhi(w.x);
    acc.y += bflo(w.y) + u * bfhi(w.y);
    acc.z += bflo(w.z) + u * bfhi(w.z);
    acc.w += bflo(w.w) + u * bfhi(w.w);
  }
  float ic = 1.0f / fmaxf((float)(end - start), 1.0f);
  float4 r = *(const float4*)(XR + (size_t)n * HID + c * 4);
  float4 h;
  h.x = acc.x * ic + r.x;
  h.y = acc.y * ic + r.y;
  h.z = acc.z * ic + r.z;
  h.w = acc.w * ic + r.w;
  h.x = h.x > 0.f ? h.x : expm1f(h.x);
  h.y = h.y > 0.f ? h.y : expm1f(h.y);
  h.z = h.z > 0.f ? h.z : expm1f(h.z);
  h.w = h.w > 0.f ? h.w : expm1f(h.w);
  uint2 hw;
  hw.x = bfpack(h.x, h.y);
  hw.y = bfpack(h.z, h.w);
  *(uint2*)(Hb + (size_t)n * 8 + c * 2) = hw;
}

// Pull pass 2: A0[n] = sum (1-u)*H[s];  A1[n] = sum u*H[s]   (f32 out)
__global__ __launch_bounds__(256) void k_pull2(const int* __restrict__ off,
    const unsigned* __restrict__ sedge, const unsigned* __restrict__ Hb,
    float* __restrict__ A0, float* __restrict__ A1) {
  int tid = blockIdx.x * 256 + threadIdx.x;
  int n = tid >> 2, c = tid & 3;
  if (n >= NN) return;
  int start = (n == 0) ? 0 : off[n - 1];
  int end = off[n];
  float4 a0 = make_float4(0.f, 0.f, 0.f, 0.f);
  float4 a1 = make_float4(0.f, 0.f, 0.f, 0.f);
  for (int i = start; i < end; ++i) {
    unsigned se = sedge[i];
    int s = se & 131071u;
    float u = (float)(se >> 17) * (1.0f / 32767.0f);
    uint2 w = *(const uint2*)(Hb + (size_t)s * 8 + c * 2);
    float h0 = bflo(w.x), h1 = bfhi(w.x), h2 = bflo(w.y), h3 = bfhi(w.y);
    a0.x += h0 - u * h0;  a1.x += u * h0;
    a0.y += h1 - u * h1;  a1.y += u * h1;
    a0.z += h2 - u * h2;  a1.z += u * h2;
    a0.w += h3 - u * h3;  a1.w += u * h3;
  }
  *(float4*)(A0 + (size_t)n * HID + c * 4) = a0;
  *(float4*)(A1 + (size_t)n * HID + c * 4) = a1;
}

// K5: out = log_softmax( (A0@W2[0] + A1@W2[1])/max(deg,1) + H@root2 + bias2 )
__global__ __launch_bounds__(256) void k_final(const float* __restrict__ A0,
    const float* __restrict__ A1, const unsigned* __restrict__ Hb,
    const int* __restrict__ off, const float* __restrict__ W2,
    const float* __restrict__ root2, const float* __restrict__ bias2,
    float* __restrict__ out) {
  __shared__ float w20[HID * NC];
  __shared__ float w21[HID * NC];
  __shared__ float r2[HID * NC];
  __shared__ float b2[NC];
  int t = threadIdx.x;
  for (int i = t; i < HID * NC; i += 256) {
    w20[i] = W2[i];
    w21[i] = W2[HID * NC + i];
    r2[i]  = root2[i];
  }
  if (t < NC) b2[t] = bias2[t];
  __syncthreads();
  int wave = t >> 6, l = t & 63;
  int n = blockIdx.x * 4 + wave;
  int k16 = l & 15;
  float a0 = A0[(size_t)n * HID + k16];
  float a1 = A1[(size_t)n * HID + k16];
  unsigned hw = Hb[(size_t)n * 8 + (k16 >> 1)];
  float hv = (k16 & 1) ? bfhi(hw) : bflo(hw);
  int deg = off[n] - ((n == 0) ? 0 : off[n - 1]);
  float ic = 1.0f / fmaxf((float)deg, 1.0f);
  int j = (l < NC) ? l : 0;
  float accm = 0.f, accr = 0.f;
#pragma unroll
  for (int k = 0; k < HID; ++k) {
    float a0k = __shfl(a0, k);
    float a1k = __shfl(a1, k);
    float hk  = __shfl(hv, k);
    accm += a0k * w20[k * NC + j] + a1k * w21[k * NC + j];
    accr += hk * r2[k * NC + j];
  }
  float logit = accm * ic + accr + b2[j];
  float mx = (l < NC) ? logit : -INFINITY;
#pragma unroll
  for (int off2 = 32; off2 >= 1; off2 >>= 1) mx = fmaxf(mx, __shfl_xor(mx, off2));
  float p = (l < NC) ? expf(logit - mx) : 0.f;
  float sm = p;
#pragma unroll
  for (int off2 = 32; off2 >= 1; off2 >>= 1) sm += __shfl_xor(sm, off2);
  if (l < NC) out[(size_t)n * NC + l] = logit - mx - logf(sm);
}

extern "C" void kernel_launch(void* const* d_in, const int* in_sizes, int n_in,
                              void* d_out, int out_size, void* d_ws, size_t ws_size,
                              hipStream_t stream) {
  const float* x     = (const float*)d_in[0];
  const int*   ei    = (const int*)d_in[1];
  const float* ea    = (const float*)d_in[2];
  const float* W1    = (const float*)d_in[3];
  const float* root1 = (const float*)d_in[4];
  const float* bias1 = (const float*)d_in[5];
  const float* W2    = (const float*)d_in[6];
  const float* root2 = (const float*)d_in[7];
  const float* bias2 = (const float*)d_in[8];
  float* out = (float*)d_out;
  char* base = (char*)d_ws;

  // Layout (bytes):
  //   [0,       6.4M)  XD  (u32[NN*16], bf16 X0|D pairs)   -> later A0 (f32[NN*16])
  //   [6.4M,   12.8M)  XR  (f32[NN*16])                    -> later A1 (f32[NN*16])
  //   [12.8M,  16.0M)  Hb  (u32[NN*8],  bf16 H pairs)
  //   [0,      25.6M)  bstream (int2[NE]) during CSR build only (dead before k_gemm1)
  //   [25.6M,  38.4M)  sedge (u32[NE], src|u15<<17)
  //   [38.4M, ...)     off[NN], bcnt, bbase, bcur
  unsigned* XD = (unsigned*)base;
  float*    XR = (float*)(base + 6400000);
  unsigned* Hb = (unsigned*)(base + 12800000);
  float*    A0 = (float*)base;
  float*    A1 = (float*)(base + 6400000);
  int2*     bstream = (int2*)base;
  unsigned* sedge = (unsigned*)(base + 25600000);
  int*      off   = (int*)(base + 38400000);
  int*      bcnt  = off + NN;
  int*      bbase = bcnt + NBUK;
  int*      bcur  = bbase + NBUK + 1;

  hipMemsetAsync(bcnt, 0, NBUK * sizeof(int), stream);

  // CSR build first (bstream aliases node tables)
  k_bcount<<<NBLK_BKT, 256, 0, stream>>>(ei, bcnt);
  k_bscan<<<1, 256, 0, stream>>>(bcnt, bbase, bcur);
  k_bucketize<<<NBLK_BKT, 256, 0, stream>>>(ei, ea, bcur, bstream);
  k_csr<<<NBUK, 512, 0, stream>>>(bstream, bbase, off, sedge);

  // Dense + pulls
  k_gemm1<<<NN / 16, 256, 0, stream>>>(x, W1, root1, bias1, XD, XR);
  k_pull1<<<(NN * 4 + 255) / 256, 256, 0, stream>>>(off, sedge, XD, XR, Hb);
  k_pull2<<<(NN * 4 + 255) / 256, 256, 0, stream>>>(off, sedge, Hb, A0, A1);
  k_final<<<NN / 4, 256, 0, stream>>>(A0, A1, Hb, off, W2, root2, bias2, out);
}

// Round 5
// 307.733 us; speedup vs baseline: 7.3042x; 1.1731x over previous
//
#include <hip/hip_runtime.h>
#include <cstddef>

#define NN 100000
#define NE 3200000
#define FIN 128
#define HID 16
#define NC 40
#define NBUK 196                 // ceil(100000 / 512) node-range buckets
#define CHUNK 4096               // edges per block in bucketing passes
#define NBLK_BKT ((NE + CHUNK - 1) / CHUNK)   // 782

// ---- bf16 helpers (RNE pack, cheap unpack) ----
__device__ __forceinline__ unsigned bf16rne(float f) {
  unsigned u = __float_as_uint(f);
  return (u + 0x7fffu + ((u >> 16) & 1u)) >> 16;
}
__device__ __forceinline__ unsigned bfpack(float lo, float hi) {
  return bf16rne(lo) | (bf16rne(hi) << 16);
}
__device__ __forceinline__ float bflo(unsigned w) { return __uint_as_float(w << 16); }
__device__ __forceinline__ float bfhi(unsigned w) { return __uint_as_float(w & 0xffff0000u); }

// ---------- CSR build: bucketed counting sort (atomic-light) ----------

__global__ __launch_bounds__(256) void k_bcount(const int* __restrict__ ei,
                                                int* __restrict__ bcnt) {
  __shared__ int h[NBUK];
  int t = threadIdx.x;
  for (int i = t; i < NBUK; i += 256) h[i] = 0;
  __syncthreads();
  int base = blockIdx.x * CHUNK;
#pragma unroll
  for (int i = 0; i < 16; ++i) {
    int e = base + i * 256 + t;
    if (e < NE) atomicAdd(&h[ei[NE + e] >> 9], 1);
  }
  __syncthreads();
  for (int i = t; i < NBUK; i += 256)
    if (h[i]) atomicAdd(&bcnt[i], h[i]);
}

__global__ __launch_bounds__(256) void k_bscan(const int* __restrict__ bcnt,
    int* __restrict__ bbase, int* __restrict__ bcur) {
  __shared__ int scn[256];
  int t = threadIdx.x;
  int v = (t < NBUK) ? bcnt[t] : 0;
  scn[t] = v;
  __syncthreads();
  for (int st = 1; st < 256; st <<= 1) {
    int tmp = (t >= st) ? scn[t - st] : 0;
    __syncthreads();
    scn[t] += tmp;
    __syncthreads();
  }
  if (t < NBUK) { int ex = scn[t] - v; bbase[t] = ex; bcur[t] = ex; }
  if (t == NBUK - 1) bbase[NBUK] = scn[t];
}

// Record: .x = (dst&511)<<17 | src   (src < 2^17), .y = bits(u)
__global__ __launch_bounds__(256) void k_bucketize(const int* __restrict__ ei,
    const float* __restrict__ ea, int* __restrict__ bcur,
    int2* __restrict__ bstream) {
  __shared__ int lh[NBUK];
  __shared__ int lbase[NBUK];
  __shared__ int gb[NBUK];
  __shared__ int scn[256];
  __shared__ int meta[CHUNK];
  __shared__ int uval[CHUNK];
  __shared__ unsigned char sbkt[CHUNK];
  int t = threadIdx.x;
  for (int i = t; i < NBUK; i += 256) lh[i] = 0;
  __syncthreads();
  int base = blockIdx.x * CHUNK;
  int rk[16], bk[16], mt[16], uv[16];
#pragma unroll
  for (int i = 0; i < 16; ++i) {
    int e = base + i * 256 + t;
    if (e < NE) {
      int d = ei[NE + e], sv = ei[e];
      int b = d >> 9;
      rk[i] = atomicAdd(&lh[b], 1);
      bk[i] = b;
      mt[i] = ((d & 511) << 17) | sv;
      uv[i] = __float_as_int(ea[e]);
    } else bk[i] = -1;
  }
  __syncthreads();
  int v = (t < NBUK) ? lh[t] : 0;
  scn[t] = v;
  __syncthreads();
  for (int st = 1; st < 256; st <<= 1) {
    int tmp = (t >= st) ? scn[t - st] : 0;
    __syncthreads();
    scn[t] += tmp;
    __syncthreads();
  }
  if (t < NBUK) lbase[t] = scn[t] - v;
  int total = scn[255];
  __syncthreads();
  if (t < NBUK && lh[t] > 0) gb[t] = atomicAdd(&bcur[t], lh[t]);
  __syncthreads();
#pragma unroll
  for (int i = 0; i < 16; ++i) {
    if (bk[i] >= 0) {
      int p = lbase[bk[i]] + rk[i];
      meta[p] = mt[i];
      uval[p] = uv[i];
      sbkt[p] = (unsigned char)bk[i];
    }
  }
  __syncthreads();
  for (int s = t; s < total; s += 256) {
    int b = sbkt[s];
    bstream[gb[b] + (s - lbase[b])] = make_int2(meta[s], uval[s]);
  }
}

// Pass D: one block per bucket -> off[] + packed sedge (src | u15<<17)
__global__ __launch_bounds__(512) void k_csr(const int2* __restrict__ bstream,
    const int* __restrict__ bbase, int* __restrict__ off,
    unsigned* __restrict__ sedge) {
  __shared__ int cnt[512];
  __shared__ int scn[512];
  __shared__ int cur[512];
  int b = blockIdx.x, t = threadIdx.x;
  int s0 = bbase[b], s1 = bbase[b + 1];
  cnt[t] = 0;
  __syncthreads();
  for (int i = s0 + t; i < s1; i += 512)
    atomicAdd(&cnt[bstream[i].x >> 17], 1);
  __syncthreads();
  int v = cnt[t];
  scn[t] = v;
  __syncthreads();
  for (int st = 1; st < 512; st <<= 1) {
    int tmp = (t >= st) ? scn[t - st] : 0;
    __syncthreads();
    scn[t] += tmp;
    __syncthreads();
  }
  int n = (b << 9) + t;
  if (n < NN) off[n] = s0 + scn[t];          // inclusive row-end
  cur[t] = s0 + scn[t] - v;                  // row start cursor
  __syncthreads();
  for (int i = s0 + t; i < s1; i += 512) {
    int2 r = bstream[i];
    int local = r.x >> 17;
    int pos = atomicAdd(&cur[local], 1);
    unsigned u15 = (unsigned)__float2int_rn(__int_as_float(r.y) * 32767.0f);
    sedge[pos] = (unsigned)(r.x & 131071) | (u15 << 17);
  }
}

// ---------- dense / pull kernels ----------

// K1: XD[n][j] = pack(X0[n][j], X1[n][j]-X0[n][j]) bf16; XR = x@root1 + bias1 (f32)
__global__ __launch_bounds__(256) void k_gemm1(const float* __restrict__ x,
    const float* __restrict__ W1, const float* __restrict__ root1,
    const float* __restrict__ bias1,
    unsigned* __restrict__ XD, float* __restrict__ XR) {
  __shared__ float wT[48][132];
  __shared__ float xs[16][132];
  int t = threadIdx.x;
  for (int i = t; i < 48 * FIN; i += 256) {
    int j = i >> 7, k = i & 127;
    float v;
    if (j < 16)      v = W1[k * 16 + j];
    else if (j < 32) v = W1[2048 + k * 16 + (j - 16)];
    else             v = root1[k * 16 + (j - 32)];
    wT[j][k] = v;
  }
  const float4* x4 = (const float4*)(x + (size_t)blockIdx.x * 16 * FIN);
  for (int i = t; i < 16 * FIN / 4; i += 256) {
    float4 v = x4[i];
    int r = i >> 5, c = (i & 31) << 2;
    *(float4*)&xs[r][c] = v;
  }
  __syncthreads();
  int nl = t >> 4, j = t & 15;
  float a0 = 0.f, a1 = 0.f, ar = 0.f;
#pragma unroll
  for (int k = 0; k < FIN; k += 4) {
    float4 xv = *(const float4*)&xs[nl][k];
    float4 w0 = *(const float4*)&wT[j][k];
    float4 w1 = *(const float4*)&wT[j + 16][k];
    float4 wr = *(const float4*)&wT[j + 32][k];
    a0 += xv.x * w0.x + xv.y * w0.y + xv.z * w0.z + xv.w * w0.w;
    a1 += xv.x * w1.x + xv.y * w1.y + xv.z * w1.z + xv.w * w1.w;
    ar += xv.x * wr.x + xv.y * wr.y + xv.z * wr.z + xv.w * wr.w;
  }
  size_t idx = (size_t)(blockIdx.x * 16 + nl) * HID + j;
  XD[idx] = bfpack(a0, a1 - a0);
  XR[idx] = ar + bias1[j];
}

// Pull pass 1:  Hb[n] = bf16(elu(mean_e(X0[s]+u*D[s]) + XR[n]))
__global__ __launch_bounds__(256) void k_pull1(const int* __restrict__ off,
    const unsigned* __restrict__ sedge, const unsigned* __restrict__ XD,
    const float* __restrict__ XR, unsigned* __restrict__ Hb) {
  int tid = blockIdx.x * 256 + threadIdx.x;
  int n = tid >> 2, c = tid & 3;
  if (n >= NN) return;
  int start = (n == 0) ? 0 : off[n - 1];
  int end = off[n];
  float4 acc = make_float4(0.f, 0.f, 0.f, 0.f);
  for (int i = start; i < end; ++i) {
    unsigned se = sedge[i];
    int s = se & 131071u;
    float u = (float)(se >> 17) * (1.0f / 32767.0f);
    uint4 w = *(const uint4*)(XD + (size_t)s * HID + c * 4);
    acc.x += bflo(w.x) + u * bfhi(w.x);
    acc.y += bflo(w.y) + u * bfhi(w.y);
    acc.z += bflo(w.z) + u * bfhi(w.z);
    acc.w += bflo(w.w) + u * bfhi(w.w);
  }
  float ic = 1.0f / fmaxf((float)(end - start), 1.0f);
  float4 r = *(const float4*)(XR + (size_t)n * HID + c * 4);
  float4 h;
  h.x = acc.x * ic + r.x;
  h.y = acc.y * ic + r.y;
  h.z = acc.z * ic + r.z;
  h.w = acc.w * ic + r.w;
  h.x = h.x > 0.f ? h.x : expm1f(h.x);
  h.y = h.y > 0.f ? h.y : expm1f(h.y);
  h.z = h.z > 0.f ? h.z : expm1f(h.z);
  h.w = h.w > 0.f ? h.w : expm1f(h.w);
  uint2 hw;
  hw.x = bfpack(h.x, h.y);
  hw.y = bfpack(h.z, h.w);
  *(uint2*)(Hb + (size_t)n * 8 + c * 2) = hw;
}

// Pull pass 2: A0[n] = sum (1-u)*H[s];  A1[n] = sum u*H[s]   (f32 out)
__global__ __launch_bounds__(256) void k_pull2(const int* __restrict__ off,
    const unsigned* __restrict__ sedge, const unsigned* __restrict__ Hb,
    float* __restrict__ A0, float* __restrict__ A1) {
  int tid = blockIdx.x * 256 + threadIdx.x;
  int n = tid >> 2, c = tid & 3;
  if (n >= NN) return;
  int start = (n == 0) ? 0 : off[n - 1];
  int end = off[n];
  float4 a0 = make_float4(0.f, 0.f, 0.f, 0.f);
  float4 a1 = make_float4(0.f, 0.f, 0.f, 0.f);
  for (int i = start; i < end; ++i) {
    unsigned se = sedge[i];
    int s = se & 131071u;
    float u = (float)(se >> 17) * (1.0f / 32767.0f);
    uint2 w = *(const uint2*)(Hb + (size_t)s * 8 + c * 2);
    float h0 = bflo(w.x), h1 = bfhi(w.x), h2 = bflo(w.y), h3 = bfhi(w.y);
    a0.x += h0 - u * h0;  a1.x += u * h0;
    a0.y += h1 - u * h1;  a1.y += u * h1;
    a0.z += h2 - u * h2;  a1.z += u * h2;
    a0.w += h3 - u * h3;  a1.w += u * h3;
  }
  *(float4*)(A0 + (size_t)n * HID + c * 4) = a0;
  *(float4*)(A1 + (size_t)n * HID + c * 4) = a1;
}

// K5: out = log_softmax( (A0@W2[0] + A1@W2[1])/max(deg,1) + H@root2 + bias2 )
// Lane j owns column j; its 48 weights live in registers. Node data loaded
// wave-uniform (readfirstlane -> scalar/broadcast loads). No LDS in the loop.
__global__ __launch_bounds__(256) void k_final(const float* __restrict__ A0,
    const float* __restrict__ A1, const unsigned* __restrict__ Hb,
    const int* __restrict__ off, const float* __restrict__ W2,
    const float* __restrict__ root2, const float* __restrict__ bias2,
    float* __restrict__ out) {
  int t = threadIdx.x;
  int l = t & 63;
  int j = (l < NC) ? l : 0;
  float w0r[HID], w1r[HID], rr[HID];
#pragma unroll
  for (int k = 0; k < HID; ++k) {
    w0r[k] = W2[k * NC + j];
    w1r[k] = W2[HID * NC + k * NC + j];
    rr[k]  = root2[k * NC + j];
  }
  float b2 = bias2[j];
  int wid = (blockIdx.x * 256 + t) >> 6;
  int nwaves = gridDim.x * 4;
  for (int n0 = wid; n0 < NN; n0 += nwaves) {
    int n = __builtin_amdgcn_readfirstlane(n0);
    const float* a0p = A0 + (size_t)n * HID;
    const float* a1p = A1 + (size_t)n * HID;
    const unsigned* hp = Hb + (size_t)n * 8;
    int e1 = off[n];
    int e0 = (n == 0) ? 0 : off[n - 1];
    float ic = 1.0f / fmaxf((float)(e1 - e0), 1.0f);
    float accm = 0.f, accr = 0.f;
#pragma unroll
    for (int k = 0; k < HID; ++k) {
      accm += a0p[k] * w0r[k];
      accm += a1p[k] * w1r[k];
      unsigned hw = hp[k >> 1];
      float hk = (k & 1) ? bfhi(hw) : bflo(hw);
      accr += hk * rr[k];
    }
    float logit = accm * ic + accr + b2;
    float mx = (l < NC) ? logit : -INFINITY;
#pragma unroll
    for (int o = 32; o >= 1; o >>= 1) mx = fmaxf(mx, __shfl_xor(mx, o));
    float p = (l < NC) ? __expf(logit - mx) : 0.f;
    float sm = p;
#pragma unroll
    for (int o = 32; o >= 1; o >>= 1) sm += __shfl_xor(sm, o);
    if (l < NC) out[(size_t)n * NC + l] = logit - mx - __logf(sm);
  }
}

extern "C" void kernel_launch(void* const* d_in, const int* in_sizes, int n_in,
                              void* d_out, int out_size, void* d_ws, size_t ws_size,
                              hipStream_t stream) {
  const float* x     = (const float*)d_in[0];
  const int*   ei    = (const int*)d_in[1];
  const float* ea    = (const float*)d_in[2];
  const float* W1    = (const float*)d_in[3];
  const float* root1 = (const float*)d_in[4];
  const float* bias1 = (const float*)d_in[5];
  const float* W2    = (const float*)d_in[6];
  const float* root2 = (const float*)d_in[7];
  const float* bias2 = (const float*)d_in[8];
  float* out = (float*)d_out;
  char* base = (char*)d_ws;

  // Layout (bytes):
  //   [0,       6.4M)  XD  (u32[NN*16], bf16 X0|D pairs)   -> later A0 (f32[NN*16])
  //   [6.4M,   12.8M)  XR  (f32[NN*16])                    -> later A1 (f32[NN*16])
  //   [12.8M,  16.0M)  Hb  (u32[NN*8],  bf16 H pairs)
  //   [0,      25.6M)  bstream (int2[NE]) during CSR build only (dead before k_gemm1)
  //   [25.6M,  38.4M)  sedge (u32[NE], src|u15<<17)
  //   [38.4M, ...)     off[NN], bcnt, bbase, bcur
  unsigned* XD = (unsigned*)base;
  float*    XR = (float*)(base + 6400000);
  unsigned* Hb = (unsigned*)(base + 12800000);
  float*    A0 = (float*)base;
  float*    A1 = (float*)(base + 6400000);
  int2*     bstream = (int2*)base;
  unsigned* sedge = (unsigned*)(base + 25600000);
  int*      off   = (int*)(base + 38400000);
  int*      bcnt  = off + NN;
  int*      bbase = bcnt + NBUK;
  int*      bcur  = bbase + NBUK + 1;

  hipMemsetAsync(bcnt, 0, NBUK * sizeof(int), stream);

  // CSR build first (bstream aliases node tables)
  k_bcount<<<NBLK_BKT, 256, 0, stream>>>(ei, bcnt);
  k_bscan<<<1, 256, 0, stream>>>(bcnt, bbase, bcur);
  k_bucketize<<<NBLK_BKT, 256, 0, stream>>>(ei, ea, bcur, bstream);
  k_csr<<<NBUK, 512, 0, stream>>>(bstream, bbase, off, sedge);

  // Dense + pulls
  k_gemm1<<<NN / 16, 256, 0, stream>>>(x, W1, root1, bias1, XD, XR);
  k_pull1<<<(NN * 4 + 255) / 256, 256, 0, stream>>>(off, sedge, XD, XR, Hb);
  k_pull2<<<(NN * 4 + 255) / 256, 256, 0, stream>>>(off, sedge, Hb, A0, A1);
  k_final<<<1024, 256, 0, stream>>>(A0, A1, Hb, off, W2, root2, bias2, out);
}

// Round 6
// 270.277 us; speedup vs baseline: 8.3165x; 1.1386x over previous
//
#include <hip/hip_runtime.h>
#include <cstddef>

#define NN 100000
#define NE 3200000
#define FIN 128
#define HID 16
#define NC 40
#define NBUK 196                 // ceil(100000 / 512) node-range buckets
#define CHUNK 4096               // edges per block in bucketing passes
#define NBLK_BKT ((NE + CHUNK - 1) / CHUNK)   // 782
#define G1_NPB 64                // nodes per block in k_gemm1
#define NBLK_G1 ((NN + G1_NPB - 1) / G1_NPB)  // 1563

// ---- bf16 helpers (RNE pack, cheap unpack) ----
__device__ __forceinline__ unsigned bf16rne(float f) {
  unsigned u = __float_as_uint(f);
  return (u + 0x7fffu + ((u >> 16) & 1u)) >> 16;
}
__device__ __forceinline__ unsigned bfpack(float lo, float hi) {
  return bf16rne(lo) | (bf16rne(hi) << 16);
}
__device__ __forceinline__ float bflo(unsigned w) { return __uint_as_float(w << 16); }
__device__ __forceinline__ float bfhi(unsigned w) { return __uint_as_float(w & 0xffff0000u); }

// ---------- CSR build: bucketed counting sort (atomic-light) ----------

__global__ __launch_bounds__(256) void k_bcount(const int* __restrict__ ei,
                                                int* __restrict__ bcnt) {
  __shared__ int h[NBUK];
  int t = threadIdx.x;
  for (int i = t; i < NBUK; i += 256) h[i] = 0;
  __syncthreads();
  int base = blockIdx.x * CHUNK;
#pragma unroll
  for (int i = 0; i < 16; ++i) {
    int e = base + i * 256 + t;
    if (e < NE) atomicAdd(&h[ei[NE + e] >> 9], 1);
  }
  __syncthreads();
  for (int i = t; i < NBUK; i += 256)
    if (h[i]) atomicAdd(&bcnt[i], h[i]);
}

__global__ __launch_bounds__(256) void k_bscan(const int* __restrict__ bcnt,
    int* __restrict__ bbase, int* __restrict__ bcur) {
  __shared__ int scn[256];
  int t = threadIdx.x;
  int v = (t < NBUK) ? bcnt[t] : 0;
  scn[t] = v;
  __syncthreads();
  for (int st = 1; st < 256; st <<= 1) {
    int tmp = (t >= st) ? scn[t - st] : 0;
    __syncthreads();
    scn[t] += tmp;
    __syncthreads();
  }
  if (t < NBUK) { int ex = scn[t] - v; bbase[t] = ex; bcur[t] = ex; }
  if (t == NBUK - 1) bbase[NBUK] = scn[t];
}

// Record: .x = (dst&511)<<17 | src   (src < 2^17), .y = bits(u)
__global__ __launch_bounds__(256) void k_bucketize(const int* __restrict__ ei,
    const float* __restrict__ ea, int* __restrict__ bcur,
    int2* __restrict__ bstream) {
  __shared__ int lh[NBUK];
  __shared__ int lbase[NBUK];
  __shared__ int gb[NBUK];
  __shared__ int scn[256];
  __shared__ int meta[CHUNK];
  __shared__ int uval[CHUNK];
  __shared__ unsigned char sbkt[CHUNK];
  int t = threadIdx.x;
  for (int i = t; i < NBUK; i += 256) lh[i] = 0;
  __syncthreads();
  int base = blockIdx.x * CHUNK;
  int rk[16], bk[16], mt[16], uv[16];
#pragma unroll
  for (int i = 0; i < 16; ++i) {
    int e = base + i * 256 + t;
    if (e < NE) {
      int d = ei[NE + e], sv = ei[e];
      int b = d >> 9;
      rk[i] = atomicAdd(&lh[b], 1);
      bk[i] = b;
      mt[i] = ((d & 511) << 17) | sv;
      uv[i] = __float_as_int(ea[e]);
    } else bk[i] = -1;
  }
  __syncthreads();
  int v = (t < NBUK) ? lh[t] : 0;
  scn[t] = v;
  __syncthreads();
  for (int st = 1; st < 256; st <<= 1) {
    int tmp = (t >= st) ? scn[t - st] : 0;
    __syncthreads();
    scn[t] += tmp;
    __syncthreads();
  }
  if (t < NBUK) lbase[t] = scn[t] - v;
  int total = scn[255];
  __syncthreads();
  if (t < NBUK && lh[t] > 0) gb[t] = atomicAdd(&bcur[t], lh[t]);
  __syncthreads();
#pragma unroll
  for (int i = 0; i < 16; ++i) {
    if (bk[i] >= 0) {
      int p = lbase[bk[i]] + rk[i];
      meta[p] = mt[i];
      uval[p] = uv[i];
      sbkt[p] = (unsigned char)bk[i];
    }
  }
  __syncthreads();
  for (int s = t; s < total; s += 256) {
    int b = sbkt[s];
    bstream[gb[b] + (s - lbase[b])] = make_int2(meta[s], uval[s]);
  }
}

// Pass D: one block per bucket -> off[] + packed sedge (src | u15<<17)
__global__ __launch_bounds__(512) void k_csr(const int2* __restrict__ bstream,
    const int* __restrict__ bbase, int* __restrict__ off,
    unsigned* __restrict__ sedge) {
  __shared__ int cnt[512];
  __shared__ int scn[512];
  __shared__ int cur[512];
  int b = blockIdx.x, t = threadIdx.x;
  int s0 = bbase[b], s1 = bbase[b + 1];
  cnt[t] = 0;
  __syncthreads();
  for (int i = s0 + t; i < s1; i += 512)
    atomicAdd(&cnt[bstream[i].x >> 17], 1);
  __syncthreads();
  int v = cnt[t];
  scn[t] = v;
  __syncthreads();
  for (int st = 1; st < 512; st <<= 1) {
    int tmp = (t >= st) ? scn[t - st] : 0;
    __syncthreads();
    scn[t] += tmp;
    __syncthreads();
  }
  int n = (b << 9) + t;
  if (n < NN) off[n] = s0 + scn[t];          // inclusive row-end
  cur[t] = s0 + scn[t] - v;                  // row start cursor
  __syncthreads();
  for (int i = s0 + t; i < s1; i += 512) {
    int2 r = bstream[i];
    int local = r.x >> 17;
    int pos = atomicAdd(&cur[local], 1);
    unsigned u15 = (unsigned)__float2int_rn(__int_as_float(r.y) * 32767.0f);
    sedge[pos] = (unsigned)(r.x & 131071) | (u15 << 17);
  }
}

// ---------- dense / pull kernels ----------

// K1: XD[n][j] = pack(X0, X1-X0) bf16; XR = x@root1 + bias1 (f32).
// Coalesced weight staging (flat read, transposed LDS write); x read directly
// from global (16-lane broadcast per row); 64 nodes/block, 4 nodes/thread.
__global__ __launch_bounds__(256) void k_gemm1(const float* __restrict__ x,
    const float* __restrict__ W1, const float* __restrict__ root1,
    const float* __restrict__ bias1,
    unsigned* __restrict__ XD, float* __restrict__ XR) {
  __shared__ float wT[48][132];   // wT[j][k]: j<16 W1[0], j<32 W1[1], else root1
  int t = threadIdx.x;
  for (int i = t; i < 2048; i += 256) {   // flat (k,j), coalesced global reads
    int k = i >> 4, j = i & 15;
    wT[j][k]      = W1[i];
    wT[j + 16][k] = W1[2048 + i];
    wT[j + 32][k] = root1[i];
  }
  __syncthreads();
  int j = t & 15, g = t >> 4;             // g in 0..15
  int nbase = blockIdx.x * G1_NPB;
  const float* xp[4];
  int nq[4];
#pragma unroll
  for (int q = 0; q < 4; ++q) {
    int n = nbase + g + 16 * q;
    nq[q] = n;
    xp[q] = x + (size_t)((n < NN) ? n : 0) * FIN;
  }
  float a0[4] = {0.f, 0.f, 0.f, 0.f};
  float a1[4] = {0.f, 0.f, 0.f, 0.f};
  float ar[4] = {0.f, 0.f, 0.f, 0.f};
  for (int k = 0; k < FIN; k += 4) {
    float4 w0 = *(const float4*)&wT[j][k];
    float4 w1 = *(const float4*)&wT[j + 16][k];
    float4 wr = *(const float4*)&wT[j + 32][k];
#pragma unroll
    for (int q = 0; q < 4; ++q) {
      float4 xv = *(const float4*)(xp[q] + k);
      a0[q] += xv.x * w0.x + xv.y * w0.y + xv.z * w0.z + xv.w * w0.w;
      a1[q] += xv.x * w1.x + xv.y * w1.y + xv.z * w1.z + xv.w * w1.w;
      ar[q] += xv.x * wr.x + xv.y * wr.y + xv.z * wr.z + xv.w * wr.w;
    }
  }
  float b1 = bias1[j];
#pragma unroll
  for (int q = 0; q < 4; ++q) {
    if (nq[q] < NN) {
      size_t idx = (size_t)nq[q] * HID + j;
      XD[idx] = bfpack(a0[q], a1[q] - a0[q]);
      XR[idx] = ar[q] + b1;
    }
  }
}

// Pull pass 1:  Hb[n] = bf16(elu(mean_e(X0[s]+u*D[s]) + XR[n]))
__global__ __launch_bounds__(256) void k_pull1(const int* __restrict__ off,
    const unsigned* __restrict__ sedge, const unsigned* __restrict__ XD,
    const float* __restrict__ XR, unsigned* __restrict__ Hb) {
  int tid = blockIdx.x * 256 + threadIdx.x;
  int n = tid >> 2, c = tid & 3;
  if (n >= NN) return;
  int start = (n == 0) ? 0 : off[n - 1];
  int end = off[n];
  float4 acc = make_float4(0.f, 0.f, 0.f, 0.f);
  for (int i = start; i < end; ++i) {
    unsigned se = sedge[i];
    int s = se & 131071u;
    float u = (float)(se >> 17) * (1.0f / 32767.0f);
    uint4 w = *(const uint4*)(XD + (size_t)s * HID + c * 4);
    acc.x += bflo(w.x) + u * bfhi(w.x);
    acc.y += bflo(w.y) + u * bfhi(w.y);
    acc.z += bflo(w.z) + u * bfhi(w.z);
    acc.w += bflo(w.w) + u * bfhi(w.w);
  }
  float ic = 1.0f / fmaxf((float)(end - start), 1.0f);
  float4 r = *(const float4*)(XR + (size_t)n * HID + c * 4);
  float4 h;
  h.x = acc.x * ic + r.x;
  h.y = acc.y * ic + r.y;
  h.z = acc.z * ic + r.z;
  h.w = acc.w * ic + r.w;
  h.x = h.x > 0.f ? h.x : expm1f(h.x);
  h.y = h.y > 0.f ? h.y : expm1f(h.y);
  h.z = h.z > 0.f ? h.z : expm1f(h.z);
  h.w = h.w > 0.f ? h.w : expm1f(h.w);
  uint2 hw;
  hw.x = bfpack(h.x, h.y);
  hw.y = bfpack(h.z, h.w);
  *(uint2*)(Hb + (size_t)n * 8 + c * 2) = hw;
}

// Pull pass 2: A0[n] = sum (1-u)*H[s];  A1[n] = sum u*H[s]   (f32 out)
__global__ __launch_bounds__(256) void k_pull2(const int* __restrict__ off,
    const unsigned* __restrict__ sedge, const unsigned* __restrict__ Hb,
    float* __restrict__ A0, float* __restrict__ A1) {
  int tid = blockIdx.x * 256 + threadIdx.x;
  int n = tid >> 2, c = tid & 3;
  if (n >= NN) return;
  int start = (n == 0) ? 0 : off[n - 1];
  int end = off[n];
  float4 a0 = make_float4(0.f, 0.f, 0.f, 0.f);
  float4 a1 = make_float4(0.f, 0.f, 0.f, 0.f);
  for (int i = start; i < end; ++i) {
    unsigned se = sedge[i];
    int s = se & 131071u;
    float u = (float)(se >> 17) * (1.0f / 32767.0f);
    uint2 w = *(const uint2*)(Hb + (size_t)s * 8 + c * 2);
    float h0 = bflo(w.x), h1 = bfhi(w.x), h2 = bflo(w.y), h3 = bfhi(w.y);
    a0.x += h0 - u * h0;  a1.x += u * h0;
    a0.y += h1 - u * h1;  a1.y += u * h1;
    a0.z += h2 - u * h2;  a1.z += u * h2;
    a0.w += h3 - u * h3;  a1.w += u * h3;
  }
  *(float4*)(A0 + (size_t)n * HID + c * 4) = a0;
  *(float4*)(A1 + (size_t)n * HID + c * 4) = a1;
}

// K5: out = log_softmax( (A0@W2[0] + A1@W2[1])/max(deg,1) + H@root2 + bias2 )
__global__ __launch_bounds__(256) void k_final(const float* __restrict__ A0,
    const float* __restrict__ A1, const unsigned* __restrict__ Hb,
    const int* __restrict__ off, const float* __restrict__ W2,
    const float* __restrict__ root2, const float* __restrict__ bias2,
    float* __restrict__ out) {
  int t = threadIdx.x;
  int l = t & 63;
  int j = (l < NC) ? l : 0;
  float w0r[HID], w1r[HID], rr[HID];
#pragma unroll
  for (int k = 0; k < HID; ++k) {
    w0r[k] = W2[k * NC + j];
    w1r[k] = W2[HID * NC + k * NC + j];
    rr[k]  = root2[k * NC + j];
  }
  float b2 = bias2[j];
  int wid = (blockIdx.x * 256 + t) >> 6;
  int nwaves = gridDim.x * 4;
  for (int n0 = wid; n0 < NN; n0 += nwaves) {
    int n = __builtin_amdgcn_readfirstlane(n0);
    const float* a0p = A0 + (size_t)n * HID;
    const float* a1p = A1 + (size_t)n * HID;
    const unsigned* hp = Hb + (size_t)n * 8;
    int e1 = off[n];
    int e0 = (n == 0) ? 0 : off[n - 1];
    float ic = 1.0f / fmaxf((float)(e1 - e0), 1.0f);
    float accm = 0.f, accr = 0.f;
#pragma unroll
    for (int k = 0; k < HID; ++k) {
      accm += a0p[k] * w0r[k];
      accm += a1p[k] * w1r[k];
      unsigned hw = hp[k >> 1];
      float hk = (k & 1) ? bfhi(hw) : bflo(hw);
      accr += hk * rr[k];
    }
    float logit = accm * ic + accr + b2;
    float mx = (l < NC) ? logit : -INFINITY;
#pragma unroll
    for (int o = 32; o >= 1; o >>= 1) mx = fmaxf(mx, __shfl_xor(mx, o));
    float p = (l < NC) ? __expf(logit - mx) : 0.f;
    float sm = p;
#pragma unroll
    for (int o = 32; o >= 1; o >>= 1) sm += __shfl_xor(sm, o);
    if (l < NC) out[(size_t)n * NC + l] = logit - mx - __logf(sm);
  }
}

extern "C" void kernel_launch(void* const* d_in, const int* in_sizes, int n_in,
                              void* d_out, int out_size, void* d_ws, size_t ws_size,
                              hipStream_t stream) {
  const float* x     = (const float*)d_in[0];
  const int*   ei    = (const int*)d_in[1];
  const float* ea    = (const float*)d_in[2];
  const float* W1    = (const float*)d_in[3];
  const float* root1 = (const float*)d_in[4];
  const float* bias1 = (const float*)d_in[5];
  const float* W2    = (const float*)d_in[6];
  const float* root2 = (const float*)d_in[7];
  const float* bias2 = (const float*)d_in[8];
  float* out = (float*)d_out;
  char* base = (char*)d_ws;

  // Layout (bytes):
  //   [0,       6.4M)  XD  (u32[NN*16], bf16 X0|D pairs)   -> later A0 (f32[NN*16])
  //   [6.4M,   12.8M)  XR  (f32[NN*16])                    -> later A1 (f32[NN*16])
  //   [12.8M,  16.0M)  Hb  (u32[NN*8],  bf16 H pairs)
  //   [0,      25.6M)  bstream (int2[NE]) during CSR build only (dead before k_gemm1)
  //   [25.6M,  38.4M)  sedge (u32[NE], src|u15<<17)
  //   [38.4M, ...)     off[NN], bcnt, bbase, bcur
  unsigned* XD = (unsigned*)base;
  float*    XR = (float*)(base + 6400000);
  unsigned* Hb = (unsigned*)(base + 12800000);
  float*    A0 = (float*)base;
  float*    A1 = (float*)(base + 6400000);
  int2*     bstream = (int2*)base;
  unsigned* sedge = (unsigned*)(base + 25600000);
  int*      off   = (int*)(base + 38400000);
  int*      bcnt  = off + NN;
  int*      bbase = bcnt + NBUK;
  int*      bcur  = bbase + NBUK + 1;

  hipMemsetAsync(bcnt, 0, NBUK * sizeof(int), stream);

  // CSR build first (bstream aliases node tables)
  k_bcount<<<NBLK_BKT, 256, 0, stream>>>(ei, bcnt);
  k_bscan<<<1, 256, 0, stream>>>(bcnt, bbase, bcur);
  k_bucketize<<<NBLK_BKT, 256, 0, stream>>>(ei, ea, bcur, bstream);
  k_csr<<<NBUK, 512, 0, stream>>>(bstream, bbase, off, sedge);

  // Dense + pulls
  k_gemm1<<<NBLK_G1, 256, 0, stream>>>(x, W1, root1, bias1, XD, XR);
  k_pull1<<<(NN * 4 + 255) / 256, 256, 0, stream>>>(off, sedge, XD, XR, Hb);
  k_pull2<<<(NN * 4 + 255) / 256, 256, 0, stream>>>(off, sedge, Hb, A0, A1);
  k_final<<<1024, 256, 0, stream>>>(A0, A1, Hb, off, W2, root2, bias2, out);
}

// Round 7
// 246.156 us; speedup vs baseline: 9.1314x; 1.0980x over previous
//
#include <hip/hip_runtime.h>
#include <cstddef>

#define NN 100000
#define NE 3200000
#define FIN 128
#define HID 16
#define NC 40
#define NBUK 196                 // ceil(100000 / 512) node-range buckets
#define CHUNK 4096               // edges per block in bucketing passes
#define NBLK_BKT ((NE + CHUNK - 1) / CHUNK)   // 782
#define NWAVE_G1 (NN / 16)       // 6250 waves, 16 nodes each
#define NBLK_G1 ((NWAVE_G1 + 3) / 4)          // 1563

typedef __attribute__((ext_vector_type(8))) short bf16x8;
typedef __attribute__((ext_vector_type(4))) float f32x4;

// ---- bf16 helpers (RNE pack, cheap unpack) ----
__device__ __forceinline__ unsigned bf16rne(float f) {
  unsigned u = __float_as_uint(f);
  return (u + 0x7fffu + ((u >> 16) & 1u)) >> 16;
}
__device__ __forceinline__ unsigned bfpack(float lo, float hi) {
  return bf16rne(lo) | (bf16rne(hi) << 16);
}
__device__ __forceinline__ float bflo(unsigned w) { return __uint_as_float(w << 16); }
__device__ __forceinline__ float bfhi(unsigned w) { return __uint_as_float(w & 0xffff0000u); }

// ---------- CSR build: bucketed counting sort (atomic-light) ----------

__global__ __launch_bounds__(256) void k_bcount(const int* __restrict__ ei,
                                                int* __restrict__ bcnt) {
  __shared__ int h[NBUK];
  int t = threadIdx.x;
  for (int i = t; i < NBUK; i += 256) h[i] = 0;
  __syncthreads();
  int base = blockIdx.x * CHUNK;
#pragma unroll
  for (int i = 0; i < 16; ++i) {
    int e = base + i * 256 + t;
    if (e < NE) atomicAdd(&h[ei[NE + e] >> 9], 1);
  }
  __syncthreads();
  for (int i = t; i < NBUK; i += 256)
    if (h[i]) atomicAdd(&bcnt[i], h[i]);
}

__global__ __launch_bounds__(256) void k_bscan(const int* __restrict__ bcnt,
    int* __restrict__ bbase, int* __restrict__ bcur) {
  __shared__ int scn[256];
  int t = threadIdx.x;
  int v = (t < NBUK) ? bcnt[t] : 0;
  scn[t] = v;
  __syncthreads();
  for (int st = 1; st < 256; st <<= 1) {
    int tmp = (t >= st) ? scn[t - st] : 0;
    __syncthreads();
    scn[t] += tmp;
    __syncthreads();
  }
  if (t < NBUK) { int ex = scn[t] - v; bbase[t] = ex; bcur[t] = ex; }
  if (t == NBUK - 1) bbase[NBUK] = scn[t];
}

// Record: .x = (dst&511)<<17 | src   (src < 2^17), .y = bits(u)
__global__ __launch_bounds__(256) void k_bucketize(const int* __restrict__ ei,
    const float* __restrict__ ea, int* __restrict__ bcur,
    int2* __restrict__ bstream) {
  __shared__ int lh[NBUK];
  __shared__ int lbase[NBUK];
  __shared__ int gb[NBUK];
  __shared__ int scn[256];
  __shared__ int meta[CHUNK];
  __shared__ int uval[CHUNK];
  __shared__ unsigned char sbkt[CHUNK];
  int t = threadIdx.x;
  for (int i = t; i < NBUK; i += 256) lh[i] = 0;
  __syncthreads();
  int base = blockIdx.x * CHUNK;
  int rk[16], bk[16], mt[16], uv[16];
#pragma unroll
  for (int i = 0; i < 16; ++i) {
    int e = base + i * 256 + t;
    if (e < NE) {
      int d = ei[NE + e], sv = ei[e];
      int b = d >> 9;
      rk[i] = atomicAdd(&lh[b], 1);
      bk[i] = b;
      mt[i] = ((d & 511) << 17) | sv;
      uv[i] = __float_as_int(ea[e]);
    } else bk[i] = -1;
  }
  __syncthreads();
  int v = (t < NBUK) ? lh[t] : 0;
  scn[t] = v;
  __syncthreads();
  for (int st = 1; st < 256; st <<= 1) {
    int tmp = (t >= st) ? scn[t - st] : 0;
    __syncthreads();
    scn[t] += tmp;
    __syncthreads();
  }
  if (t < NBUK) lbase[t] = scn[t] - v;
  int total = scn[255];
  __syncthreads();
  if (t < NBUK && lh[t] > 0) gb[t] = atomicAdd(&bcur[t], lh[t]);
  __syncthreads();
#pragma unroll
  for (int i = 0; i < 16; ++i) {
    if (bk[i] >= 0) {
      int p = lbase[bk[i]] + rk[i];
      meta[p] = mt[i];
      uval[p] = uv[i];
      sbkt[p] = (unsigned char)bk[i];
    }
  }
  __syncthreads();
  for (int s = t; s < total; s += 256) {
    int b = sbkt[s];
    bstream[gb[b] + (s - lbase[b])] = make_int2(meta[s], uval[s]);
  }
}

// Pass D: one block per bucket -> off[] + packed sedge (src | u15<<17)
__global__ __launch_bounds__(512) void k_csr(const int2* __restrict__ bstream,
    const int* __restrict__ bbase, int* __restrict__ off,
    unsigned* __restrict__ sedge) {
  __shared__ int cnt[512];
  __shared__ int scn[512];
  __shared__ int cur[512];
  int b = blockIdx.x, t = threadIdx.x;
  int s0 = bbase[b], s1 = bbase[b + 1];
  cnt[t] = 0;
  __syncthreads();
  for (int i = s0 + t; i < s1; i += 512)
    atomicAdd(&cnt[bstream[i].x >> 17], 1);
  __syncthreads();
  int v = cnt[t];
  scn[t] = v;
  __syncthreads();
  for (int st = 1; st < 512; st <<= 1) {
    int tmp = (t >= st) ? scn[t - st] : 0;
    __syncthreads();
    scn[t] += tmp;
    __syncthreads();
  }
  int n = (b << 9) + t;
  if (n < NN) off[n] = s0 + scn[t];          // inclusive row-end
  cur[t] = s0 + scn[t] - v;                  // row start cursor
  __syncthreads();
  for (int i = s0 + t; i < s1; i += 512) {
    int2 r = bstream[i];
    int local = r.x >> 17;
    int pos = atomicAdd(&cur[local], 1);
    unsigned u15 = (unsigned)__float2int_rn(__int_as_float(r.y) * 32767.0f);
    sedge[pos] = (unsigned)(r.x & 131071) | (u15 << 17);
  }
}

// ---------- dense / pull kernels ----------

// K1 (MFMA): one wave computes 16 nodes x 48 cols of x @ [W1[0]|W1[1]|root1].
// A[l&15][8*(l>>4)+b] per k-step; B[8*(l>>4)+b][l&15]; D col=l&15, row=4*(l>>4)+r.
__global__ __launch_bounds__(256) void k_gemm1(const float* __restrict__ x,
    const float* __restrict__ W1, const float* __restrict__ root1,
    const float* __restrict__ bias1,
    unsigned* __restrict__ XD, float* __restrict__ XR) {
  int t = threadIdx.x;
  int l = t & 63;
  int wv = (blockIdx.x * 256 + t) >> 6;
  int nb = wv * 16;
  if (nb >= NN) return;
  int j16 = l & 15, kg = l >> 4;

  // Preload 12 B fragments (weights) into VGPRs as bf16
  bf16x8 bfrag[3][4];
  const float* wsrc0 = W1;
  const float* wsrc1 = W1 + 2048;
  const float* wsrc2 = root1;
#pragma unroll
  for (int kk = 0; kk < 4; ++kk) {
    int krow = kk * 32 + kg * 8;
#pragma unroll
    for (int b = 0; b < 8; ++b) {
      int o = (krow + b) * 16 + j16;
      bfrag[0][kk][b] = (short)bf16rne(wsrc0[o]);
      bfrag[1][kk][b] = (short)bf16rne(wsrc1[o]);
      bfrag[2][kk][b] = (short)bf16rne(wsrc2[o]);
    }
  }

  f32x4 acc0 = {0.f, 0.f, 0.f, 0.f};
  f32x4 acc1 = {0.f, 0.f, 0.f, 0.f};
  f32x4 acc2 = {0.f, 0.f, 0.f, 0.f};
  const float* xrow = x + (size_t)(nb + j16) * FIN + kg * 8;
#pragma unroll
  for (int kk = 0; kk < 4; ++kk) {
    float4 xa = *(const float4*)(xrow + kk * 32);
    float4 xb = *(const float4*)(xrow + kk * 32 + 4);
    bf16x8 a;
    a[0] = (short)bf16rne(xa.x); a[1] = (short)bf16rne(xa.y);
    a[2] = (short)bf16rne(xa.z); a[3] = (short)bf16rne(xa.w);
    a[4] = (short)bf16rne(xb.x); a[5] = (short)bf16rne(xb.y);
    a[6] = (short)bf16rne(xb.z); a[7] = (short)bf16rne(xb.w);
    acc0 = __builtin_amdgcn_mfma_f32_16x16x32_bf16(a, bfrag[0][kk], acc0, 0, 0, 0);
    acc1 = __builtin_amdgcn_mfma_f32_16x16x32_bf16(a, bfrag[1][kk], acc1, 0, 0, 0);
    acc2 = __builtin_amdgcn_mfma_f32_16x16x32_bf16(a, bfrag[2][kk], acc2, 0, 0, 0);
  }

  float bb = bias1[j16];
#pragma unroll
  for (int r = 0; r < 4; ++r) {
    int n = nb + kg * 4 + r;
    size_t idx = (size_t)n * HID + j16;
    XD[idx] = bfpack(acc0[r], acc1[r] - acc0[r]);
    XR[idx] = acc2[r] + bb;
  }
}

// Pull pass 1:  Hb[n] = bf16(elu(mean_e(X0[s]+u*D[s]) + XR[n]))
__global__ __launch_bounds__(256) void k_pull1(const int* __restrict__ off,
    const unsigned* __restrict__ sedge, const unsigned* __restrict__ XD,
    const float* __restrict__ XR, unsigned* __restrict__ Hb) {
  int tid = blockIdx.x * 256 + threadIdx.x;
  int n = tid >> 2, c = tid & 3;
  if (n >= NN) return;
  int start = (n == 0) ? 0 : off[n - 1];
  int end = off[n];
  float4 acc = make_float4(0.f, 0.f, 0.f, 0.f);
  for (int i = start; i < end; ++i) {
    unsigned se = sedge[i];
    int s = se & 131071u;
    float u = (float)(se >> 17) * (1.0f / 32767.0f);
    uint4 w = *(const uint4*)(XD + (size_t)s * HID + c * 4);
    acc.x += bflo(w.x) + u * bfhi(w.x);
    acc.y += bflo(w.y) + u * bfhi(w.y);
    acc.z += bflo(w.z) + u * bfhi(w.z);
    acc.w += bflo(w.w) + u * bfhi(w.w);
  }
  float ic = 1.0f / fmaxf((float)(end - start), 1.0f);
  float4 r = *(const float4*)(XR + (size_t)n * HID + c * 4);
  float4 h;
  h.x = acc.x * ic + r.x;
  h.y = acc.y * ic + r.y;
  h.z = acc.z * ic + r.z;
  h.w = acc.w * ic + r.w;
  h.x = h.x > 0.f ? h.x : expm1f(h.x);
  h.y = h.y > 0.f ? h.y : expm1f(h.y);
  h.z = h.z > 0.f ? h.z : expm1f(h.z);
  h.w = h.w > 0.f ? h.w : expm1f(h.w);
  uint2 hw;
  hw.x = bfpack(h.x, h.y);
  hw.y = bfpack(h.z, h.w);
  *(uint2*)(Hb + (size_t)n * 8 + c * 2) = hw;
}

// Pull pass 2: A0[n] = sum (1-u)*H[s];  A1[n] = sum u*H[s]   (f32 out)
__global__ __launch_bounds__(256) void k_pull2(const int* __restrict__ off,
    const unsigned* __restrict__ sedge, const unsigned* __restrict__ Hb,
    float* __restrict__ A0, float* __restrict__ A1) {
  int tid = blockIdx.x * 256 + threadIdx.x;
  int n = tid >> 2, c = tid & 3;
  if (n >= NN) return;
  int start = (n == 0) ? 0 : off[n - 1];
  int end = off[n];
  float4 a0 = make_float4(0.f, 0.f, 0.f, 0.f);
  float4 a1 = make_float4(0.f, 0.f, 0.f, 0.f);
  for (int i = start; i < end; ++i) {
    unsigned se = sedge[i];
    int s = se & 131071u;
    float u = (float)(se >> 17) * (1.0f / 32767.0f);
    uint2 w = *(const uint2*)(Hb + (size_t)s * 8 + c * 2);
    float h0 = bflo(w.x), h1 = bfhi(w.x), h2 = bflo(w.y), h3 = bfhi(w.y);
    a0.x += h0 - u * h0;  a1.x += u * h0;
    a0.y += h1 - u * h1;  a1.y += u * h1;
    a0.z += h2 - u * h2;  a1.z += u * h2;
    a0.w += h3 - u * h3;  a1.w += u * h3;
  }
  *(float4*)(A0 + (size_t)n * HID + c * 4) = a0;
  *(float4*)(A1 + (size_t)n * HID + c * 4) = a1;
}

// K5: out = log_softmax( (A0@W2[0] + A1@W2[1])/max(deg,1) + H@root2 + bias2 )
__global__ __launch_bounds__(256) void k_final(const float* __restrict__ A0,
    const float* __restrict__ A1, const unsigned* __restrict__ Hb,
    const int* __restrict__ off, const float* __restrict__ W2,
    const float* __restrict__ root2, const float* __restrict__ bias2,
    float* __restrict__ out) {
  int t = threadIdx.x;
  int l = t & 63;
  int j = (l < NC) ? l : 0;
  float w0r[HID], w1r[HID], rr[HID];
#pragma unroll
  for (int k = 0; k < HID; ++k) {
    w0r[k] = W2[k * NC + j];
    w1r[k] = W2[HID * NC + k * NC + j];
    rr[k]  = root2[k * NC + j];
  }
  float b2 = bias2[j];
  int wid = (blockIdx.x * 256 + t) >> 6;
  int nwaves = gridDim.x * 4;
  for (int n0 = wid; n0 < NN; n0 += nwaves) {
    int n = __builtin_amdgcn_readfirstlane(n0);
    const float* a0p = A0 + (size_t)n * HID;
    const float* a1p = A1 + (size_t)n * HID;
    const unsigned* hp = Hb + (size_t)n * 8;
    int e1 = off[n];
    int e0 = (n == 0) ? 0 : off[n - 1];
    float ic = 1.0f / fmaxf((float)(e1 - e0), 1.0f);
    float accm = 0.f, accr = 0.f;
#pragma unroll
    for (int k = 0; k < HID; ++k) {
      accm += a0p[k] * w0r[k];
      accm += a1p[k] * w1r[k];
      unsigned hw = hp[k >> 1];
      float hk = (k & 1) ? bfhi(hw) : bflo(hw);
      accr += hk * rr[k];
    }
    float logit = accm * ic + accr + b2;
    float mx = (l < NC) ? logit : -INFINITY;
#pragma unroll
    for (int o = 32; o >= 1; o >>= 1) mx = fmaxf(mx, __shfl_xor(mx, o));
    float p = (l < NC) ? __expf(logit - mx) : 0.f;
    float sm = p;
#pragma unroll
    for (int o = 32; o >= 1; o >>= 1) sm += __shfl_xor(sm, o);
    if (l < NC) out[(size_t)n * NC + l] = logit - mx - __logf(sm);
  }
}

extern "C" void kernel_launch(void* const* d_in, const int* in_sizes, int n_in,
                              void* d_out, int out_size, void* d_ws, size_t ws_size,
                              hipStream_t stream) {
  const float* x     = (const float*)d_in[0];
  const int*   ei    = (const int*)d_in[1];
  const float* ea    = (const float*)d_in[2];
  const float* W1    = (const float*)d_in[3];
  const float* root1 = (const float*)d_in[4];
  const float* bias1 = (const float*)d_in[5];
  const float* W2    = (const float*)d_in[6];
  const float* root2 = (const float*)d_in[7];
  const float* bias2 = (const float*)d_in[8];
  float* out = (float*)d_out;
  char* base = (char*)d_ws;

  // Layout (bytes):
  //   [0,       6.4M)  XD  (u32[NN*16], bf16 X0|D pairs)   -> later A0 (f32[NN*16])
  //   [6.4M,   12.8M)  XR  (f32[NN*16])                    -> later A1 (f32[NN*16])
  //   [12.8M,  16.0M)  Hb  (u32[NN*8],  bf16 H pairs)
  //   [0,      25.6M)  bstream (int2[NE]) during CSR build only (dead before k_gemm1)
  //   [25.6M,  38.4M)  sedge (u32[NE], src|u15<<17)
  //   [38.4M, ...)     off[NN], bcnt, bbase, bcur
  unsigned* XD = (unsigned*)base;
  float*    XR = (float*)(base + 6400000);
  unsigned* Hb = (unsigned*)(base + 12800000);
  float*    A0 = (float*)base;
  float*    A1 = (float*)(base + 6400000);
  int2*     bstream = (int2*)base;
  unsigned* sedge = (unsigned*)(base + 25600000);
  int*      off   = (int*)(base + 38400000);
  int*      bcnt  = off + NN;
  int*      bbase = bcnt + NBUK;
  int*      bcur  = bbase + NBUK + 1;

  hipMemsetAsync(bcnt, 0, NBUK * sizeof(int), stream);

  // CSR build first (bstream aliases node tables)
  k_bcount<<<NBLK_BKT, 256, 0, stream>>>(ei, bcnt);
  k_bscan<<<1, 256, 0, stream>>>(bcnt, bbase, bcur);
  k_bucketize<<<NBLK_BKT, 256, 0, stream>>>(ei, ea, bcur, bstream);
  k_csr<<<NBUK, 512, 0, stream>>>(bstream, bbase, off, sedge);

  // Dense + pulls
  k_gemm1<<<NBLK_G1, 256, 0, stream>>>(x, W1, root1, bias1, XD, XR);
  k_pull1<<<(NN * 4 + 255) / 256, 256, 0, stream>>>(off, sedge, XD, XR, Hb);
  k_pull2<<<(NN * 4 + 255) / 256, 256, 0, stream>>>(off, sedge, Hb, A0, A1);
  k_final<<<1024, 256, 0, stream>>>(A0, A1, Hb, off, W2, root2, bias2, out);
}